// Round 7
// baseline (4260.819 us; speedup 1.0000x reference)
//
#include <hip/hip_runtime.h>
#include <hip/hip_bf16.h>
#include <cmath>

typedef __hip_bfloat16 bf16;

#define B_   32
#define T_   252
#define F_   8
#define D_   512
#define NH_  8
#define DH_  64
#define DI_  1024
#define DHI_ 128
#define FF_  682
#define FF2_ 1364
#define FFP_ 704
#define BT_  (B_*T_)
#define EPS_ 1e-5f

typedef __attribute__((ext_vector_type(8))) short short8;
typedef __attribute__((ext_vector_type(4))) float floatx4;

__device__ __forceinline__ float b2f(bf16 v){ return __bfloat162float(v); }
__device__ __forceinline__ float siluf(float x){ return x/(1.f+expf(-x)); }
__device__ __forceinline__ float geluf(float x){
  float x3 = x*x*x;
  return 0.5f*x*(1.f+tanhf(0.7978845608028654f*(x+0.044715f*x3)));
}
__device__ __forceinline__ float ldin(const void* p, long i, int isbf){
  return isbf ? __bfloat162float(((const bf16*)p)[i]) : ((const float*)p)[i];
}
__device__ __forceinline__ unsigned short f2bu(float f){
  bf16 h = __float2bfloat16(f);
  return *(reinterpret_cast<unsigned short*>(&h));
}
__device__ __forceinline__ void split2(float v, unsigned short& h, unsigned short& l){
  bf16 hb = __float2bfloat16(v);
  h = *(reinterpret_cast<unsigned short*>(&hb));
  float r = v - __bfloat162float(hb);
  bf16 lb = __float2bfloat16(r);
  l = *(reinterpret_cast<unsigned short*>(&lb));
}
__device__ __forceinline__ unsigned packbf(float x, float y){
  return (unsigned)f2bu(x) | ((unsigned)f2bu(y) << 16);
}

__global__ void detect_dtype(const unsigned* __restrict__ probe, int* __restrict__ flag)
{
  if (threadIdx.x == 0) *flag = (*probe == 0x3F803F80u) ? 1 : 0;
}

// ---- sLSTM recurrent weight prep: Rg [si][g][hd][d][e] -> fp32 [(si*4+g)*8+hd][e][d] ----
__global__ __launch_bounds__(256) void rg_prep(
    const void* __restrict__ Rg, float* __restrict__ out, const int* __restrict__ dflag)
{
  const int isbf = *dflag;
  const int c = blockIdx.x;          // 0..127 = (si*4+g)*8+hd
  const long base = (long)c*4096;
  __shared__ float tl[64][65];
  const int col = threadIdx.x & 63, r4 = threadIdx.x >> 6;
#pragma unroll
  for (int i=0;i<16;i++){
    int d = i*4 + r4;
    tl[d][col] = ldin(Rg, base + (long)d*64 + col, isbf);
  }
  __syncthreads();
#pragma unroll
  for (int i=0;i<16;i++){
    int e = i*4 + r4;
    out[base + (long)e*64 + col] = tl[col][e];
  }
}

// ---- weight transpose + hi/lo bf16 split: in [K][N] -> planes [N][outK] (outK>=K zero-pad) ----
__global__ __launch_bounds__(256) void wt_transpose2(
    const void* __restrict__ in, long inOff, long inStride, int K, int N, int outK,
    unsigned short* __restrict__ outHi, unsigned short* __restrict__ outLo,
    long outStride, const int* __restrict__ dflag)
{
  const int isbf = *dflag;
  const int bz = blockIdx.z;
  const long base = inOff + (long)bz*inStride;
  unsigned short* oh = outHi + (long)bz*outStride;
  unsigned short* ol = outLo ? outLo + (long)bz*outStride : nullptr;
  __shared__ float tile[32][33];
  const int k0 = blockIdx.y*32, n0 = blockIdx.x*32;
  const int tn = threadIdx.x & 31, tk = threadIdx.x >> 5;
#pragma unroll
  for (int i=0;i<4;i++){
    int kk = tk + i*8;
    float v = 0.f;
    if (k0+kk < K && n0+tn < N) v = ldin(in, base + (long)(k0+kk)*N + n0+tn, isbf);
    tile[kk][tn] = v;
  }
  __syncthreads();
#pragma unroll
  for (int i=0;i<4;i++){
    int nn = tk + i*8;
    if (n0+nn < N && k0+tn < outK){
      unsigned short h, l;
      split2(tile[tn][nn], h, l);
      oh[(long)(n0+nn)*outK + k0+tn] = h;
      if (ol) ol[(long)(n0+nn)*outK + k0+tn] = l;
    }
  }
}

// ---- split-bf16 MFMA GEMM: C = alpha*(A@B) [+bias] [+C] ----
// flags: 1=bias, 2=accumulate, 8=store C as packed bf16 (ushort)
__global__ __launch_bounds__(256) void gemm_split(
    const float* __restrict__ A0, const float* __restrict__ A1, int zSplit, long strideA,
    const unsigned short* __restrict__ Bhi, const unsigned short* __restrict__ Blo,
    const void* __restrict__ bias, long offBias, float* __restrict__ C,
    int N, int K, int lda, int ldc,
    long strideBT, long strideC, long strideBias,
    float alpha, int flags, int splitB, const int* __restrict__ dflag)
{
  const int isbf = *dflag;
  const int bz = blockIdx.z;
  const float* A = ((bz < zSplit) ? A0 : A1) + (long)bz*strideA;
  const unsigned short* bhp = Bhi + (long)bz*strideBT;
  const unsigned short* blp = Blo + (long)bz*strideBT;
  const long cBase = (long)bz*strideC;
  const long bBias = offBias + (long)bz*strideBias;

  __shared__ unsigned short aH[64*72], aL[64*72], bH[64*72], bL[64*72];
  const int tid = threadIdx.x;
  const int wid = tid >> 6, lane = tid & 63;
  const int wm = (wid >> 1)*32, wn = (wid & 1)*32;
  const int m0 = blockIdx.y*64, n0 = blockIdx.x*64;
  const int lr = lane & 15, lq = lane >> 4;

  floatx4 acc[2][2];
#pragma unroll
  for (int mi=0;mi<2;mi++)
#pragma unroll
    for (int ni=0;ni<2;ni++)
#pragma unroll
      for (int r=0;r<4;r++) acc[mi][ni][r] = 0.f;

  const int sRow = tid >> 2;
  const int sSeg = (tid & 3)*16;

  for (int k0 = 0; k0 < K; k0 += 64) {
    {
      const float* ap = A + (long)(m0 + sRow)*lda + k0 + sSeg;
#pragma unroll
      for (int c=0;c<4;c++){
        const float4 v = *(const float4*)(ap + c*4);
        unsigned short h0,h1,h2,h3,l0,l1,l2,l3;
        split2(v.x,h0,l0); split2(v.y,h1,l1); split2(v.z,h2,l2); split2(v.w,h3,l3);
        uint2 ph, pl;
        ph.x = (unsigned)h0 | ((unsigned)h1<<16); ph.y = (unsigned)h2 | ((unsigned)h3<<16);
        pl.x = (unsigned)l0 | ((unsigned)l1<<16); pl.y = (unsigned)l2 | ((unsigned)l3<<16);
        *(uint2*)&aH[sRow*72 + sSeg + c*4] = ph;
        *(uint2*)&aL[sRow*72 + sSeg + c*4] = pl;
      }
    }
    {
      const int gn = n0 + sRow;
      const bool nv = gn < N;
      const long bo = (long)gn*K + k0 + sSeg;
      uint4 z4; z4.x=z4.y=z4.z=z4.w=0;
      uint4 h0 = nv ? *(const uint4*)(bhp + bo)     : z4;
      uint4 h1 = nv ? *(const uint4*)(bhp + bo + 8) : z4;
      *(uint4*)&bH[sRow*72 + sSeg]     = h0;
      *(uint4*)&bH[sRow*72 + sSeg + 8] = h1;
      if (splitB){
        uint4 l0_ = nv ? *(const uint4*)(blp + bo)     : z4;
        uint4 l1_ = nv ? *(const uint4*)(blp + bo + 8) : z4;
        *(uint4*)&bL[sRow*72 + sSeg]     = l0_;
        *(uint4*)&bL[sRow*72 + sSeg + 8] = l1_;
      }
    }
    __syncthreads();

#pragma unroll
    for (int ks=0;ks<2;ks++){
      short8 ah[2], al[2], bh_[2], bl_[2];
#pragma unroll
      for (int mi=0;mi<2;mi++){
        ah[mi] = *(const short8*)&aH[(wm+mi*16+lr)*72 + ks*32 + lq*8];
        al[mi] = *(const short8*)&aL[(wm+mi*16+lr)*72 + ks*32 + lq*8];
      }
#pragma unroll
      for (int ni=0;ni<2;ni++){
        bh_[ni] = *(const short8*)&bH[(wn+ni*16+lr)*72 + ks*32 + lq*8];
        if (splitB) bl_[ni] = *(const short8*)&bL[(wn+ni*16+lr)*72 + ks*32 + lq*8];
      }
#pragma unroll
      for (int mi=0;mi<2;mi++)
#pragma unroll
        for (int ni=0;ni<2;ni++){
          acc[mi][ni] = __builtin_amdgcn_mfma_f32_16x16x32_bf16(al[mi], bh_[ni], acc[mi][ni], 0,0,0);
          if (splitB)
            acc[mi][ni] = __builtin_amdgcn_mfma_f32_16x16x32_bf16(ah[mi], bl_[ni], acc[mi][ni], 0,0,0);
          acc[mi][ni] = __builtin_amdgcn_mfma_f32_16x16x32_bf16(ah[mi], bh_[ni], acc[mi][ni], 0,0,0);
        }
    }
    __syncthreads();
  }

#pragma unroll
  for (int mi=0;mi<2;mi++){
#pragma unroll
    for (int ni=0;ni<2;ni++){
      const int gn = n0 + wn + ni*16 + lr;
      if (gn >= N) continue;
      const float bv = (flags & 1) ? ldin(bias, bBias + gn, isbf) : 0.f;
#pragma unroll
      for (int rr=0;rr<4;rr++){
        const int gm = m0 + wm + mi*16 + lq*4 + rr;
        float vv = acc[mi][ni][rr]*alpha + bv;
        const long idx = cBase + (long)gm*ldc + gn;
        if (flags & 8) {
          ((unsigned short*)C)[idx] = f2bu(vv);
        } else {
          if (flags & 2) vv += C[idx];
          C[idx] = vv;
        }
      }
    }
  }
}

// ---------------- input projection + layernorm ----------------
__global__ __launch_bounds__(256) void ln_proj(
    const void* __restrict__ x, const void* __restrict__ w,
    const void* __restrict__ bb, const void* __restrict__ s,
    const void* __restrict__ b, float* __restrict__ out,
    const int* __restrict__ dflag)
{
  const int isbf = *dflag;
  const int r = blockIdx.x;
  const int tid = threadIdx.x;
  float xr[8];
#pragma unroll
  for (int f = 0; f < 8; f++) xr[f] = ldin(x, (long)r*8+f, isbf);
  float vv[2];
#pragma unroll
  for (int i2 = 0; i2 < 2; i2++) {
    const int j = tid + i2*256;
    float a = ldin(bb, j, isbf);
#pragma unroll
    for (int f = 0; f < 8; f++) a += xr[f]*ldin(w, f*512+j, isbf);
    vv[i2] = a;
  }
  __shared__ float r1[256], r2[256];
  r1[tid] = vv[0]+vv[1]; r2[tid] = vv[0]*vv[0]+vv[1]*vv[1];
  __syncthreads();
  for (int o = 128; o > 0; o >>= 1) {
    if (tid < o) { r1[tid]+=r1[tid+o]; r2[tid]+=r2[tid+o]; }
    __syncthreads();
  }
  const float mu = r1[0]*(1.f/512.f);
  const float var = r2[0]*(1.f/512.f)-mu*mu;
  const float rstd = rsqrtf(var+EPS_);
  float* orow = out + (long)r*512;
#pragma unroll
  for (int i2 = 0; i2 < 2; i2++) {
    const int j = tid + i2*256;
    orow[j] = (vv[i2]-mu)*rstd*ldin(s, j, isbf) + ldin(b, j, isbf);
  }
}

// ---------------- layernorm over 512-elem rows ----------------
__global__ __launch_bounds__(256) void ln_rows(
    const float* __restrict__ in, long rowStride,
    const void* __restrict__ s, long offS,
    const void* __restrict__ b, long offB,
    float* __restrict__ out, const int* __restrict__ dflag)
{
  const int isbf = *dflag;
  const long r = blockIdx.x;
  const int tid = threadIdx.x;
  const float* xr = in + r*rowStride;
  const float v0 = xr[tid], v1 = xr[tid+256];
  __shared__ float r1[256], r2[256];
  r1[tid] = v0+v1; r2[tid] = v0*v0+v1*v1;
  __syncthreads();
  for (int o = 128; o > 0; o >>= 1) {
    if (tid < o) { r1[tid]+=r1[tid+o]; r2[tid]+=r2[tid+o]; }
    __syncthreads();
  }
  const float mu = r1[0]*(1.f/512.f);
  const float var = r2[0]*(1.f/512.f)-mu*mu;
  const float rstd = rsqrtf(var+EPS_);
  float* orow = out + r*(long)D_;
  orow[tid]     = (v0-mu)*rstd*ldin(s, offS+tid, isbf)     + ldin(b, offB+tid, isbf);
  orow[tid+256] = (v1-mu)*rstd*ldin(s, offS+tid+256, isbf) + ldin(b, offB+tid+256, isbf);
}

// ---------------- causal conv(K=4) + silu ----------------
__global__ void conv_silu(const float* __restrict__ in, int inStride,
                          const void* __restrict__ w, long offW,
                          const void* __restrict__ bias, long offBias,
                          float* __restrict__ out, int Dc,
                          const int* __restrict__ dflag)
{
  const int isbf = *dflag;
  const long total = (long)BT_ * Dc;
  for (long idx = (long)blockIdx.x*256 + threadIdx.x; idx < total;
       idx += (long)gridDim.x*256) {
    const int d = (int)(idx % Dc);
    const long bt = idx / Dc;
    const int b = (int)(bt / T_), t = (int)(bt % T_);
    float a = ldin(bias, offBias + d, isbf);
#pragma unroll
    for (int kk = 0; kk < 4; kk++) {
      const int ts = t - 3 + kk;
      if (ts >= 0) a += ldin(w, offW + kk*Dc + d, isbf) * in[((long)(b*T_+ts))*inStride + d];
    }
    out[idx] = siluf(a);
  }
}

// ---------------- fallback SIMT GEMM ----------------
__global__ __launch_bounds__(256) void gemm_f32b(
    const float* __restrict__ A, const void* __restrict__ Bw, long offB,
    const void* __restrict__ bias, long offBias, float* __restrict__ C,
    int M, int N, int K, int lda, int ldb, int ldc,
    long strideA, long strideB, long strideC, long strideBias,
    float alpha, int flags, const int* __restrict__ dflag)
{
  const int isbf = *dflag;
  const int bz = blockIdx.z;
  A  += (long)bz * strideA;
  const long bB = offB + (long)bz * strideB;
  const long cBase = (long)bz * strideC;
  const long bBias = offBias + (long)bz * strideBias;
  __shared__ float sA[16][68];
  __shared__ float sB[16][64];
  const int tid = threadIdx.x;
  const int tx = tid & 15, ty = tid >> 4;
  const int m0 = blockIdx.y * 64, n0 = blockIdx.x * 64;
  float acc[4][4];
#pragma unroll
  for (int i=0;i<4;i++)
#pragma unroll
    for (int j=0;j<4;j++) acc[i][j]=0.f;

  for (int k0 = 0; k0 < K; k0 += 16) {
#pragma unroll
    for (int r = 0; r < 4; r++) {
      int lin = tid + r*256;
      int kk = lin & 15, m = lin >> 4;
      int gm = m0 + m, gk = k0 + kk;
      sA[kk][m] = (gm < M && gk < K) ? A[(long)gm*lda + gk] : 0.f;
    }
#pragma unroll
    for (int r = 0; r < 4; r++) {
      int lin = tid + r*256;
      int nn = lin & 63, kk = lin >> 6;
      int gn = n0 + nn, gk = k0 + kk;
      sB[kk][nn] = (gn < N && gk < K) ? ldin(Bw, bB + (long)gk*ldb + gn, isbf) : 0.f;
    }
    __syncthreads();
#pragma unroll
    for (int kk = 0; kk < 16; kk++) {
      const float4 a4 = *(const float4*)(&sA[kk][ty*4]);
      const float4 b4 = *(const float4*)(&sB[kk][tx*4]);
      float av[4] = {a4.x, a4.y, a4.z, a4.w};
      float bv[4] = {b4.x, b4.y, b4.z, b4.w};
#pragma unroll
      for (int i=0;i<4;i++)
#pragma unroll
        for (int j=0;j<4;j++) acc[i][j] += av[i]*bv[j];
    }
    __syncthreads();
  }
#pragma unroll
  for (int i=0;i<4;i++) {
    const int gm = m0 + ty*4 + i;
    if (gm >= M) continue;
#pragma unroll
    for (int j=0;j<4;j++) {
      const int gn = n0 + tx*4 + j;
      if (gn >= N) continue;
      float vv = acc[i][j]*alpha;
      if (flags & 1) vv += ldin(bias, bBias + gn, isbf);
      if (flags & 4) vv = geluf(vv);
      const long idx = cBase + (long)gm*ldc + gn;
      if (flags & 8) {
        ((unsigned short*)C)[idx] = f2bu(vv);
      } else {
        if (flags & 2) vv += C[idx];
        C[idx] = vv;
      }
    }
  }
}

// ---------------- sLSTM scan v2: 128 threads (2 waves), 2 gates/thread ----------------
// weights pre-transposed fp32 [(g)*8+hd][e][d] (d contiguous) -> kept in VGPRs
__global__ __launch_bounds__(128, 1) void slstm_scan2(
    const float* __restrict__ g4, const float* __restrict__ wR,
    float* __restrict__ hs)
{
  const int blk = blockIdx.x;
  const int b = blk >> 3, hd = blk & 7;
  const int tid = threadIdx.x;
  const int e = tid & 63, gp = tid >> 6;   // gp=0 -> gates 0,1 ; gp=1 -> gates 2,3

  float w0[64], w1[64];
  {
    const float* p0 = wR + (((long)(gp*2)*8 + hd)*64 + e)*64;
    const float* p1 = wR + (((long)(gp*2+1)*8 + hd)*64 + e)*64;
#pragma unroll
    for (int d4 = 0; d4 < 16; d4++){
      const float4 a = *(const float4*)(p0 + d4*4);
      const float4 c = *(const float4*)(p1 + d4*4);
      w0[d4*4+0]=a.x; w0[d4*4+1]=a.y; w0[d4*4+2]=a.z; w0[d4*4+3]=a.w;
      w1[d4*4+0]=c.x; w1[d4*4+1]=c.y; w1[d4*4+2]=c.z; w1[d4*4+3]=c.w;
    }
  }

  __shared__ float hlds[64];
  __shared__ float rec[4][64];
  if (tid < 64) hlds[tid] = 0.f;
  float c = 0.f, n = 0.f, m = 0.f;
  __syncthreads();

  const long gbase = (long)(b*T_)*D_ + hd*64 + e;
  const long go0 = (long)(gp*2)*BT_*D_ + gbase;
  const long go1 = (long)(gp*2+1)*BT_*D_ + gbase;
  float gn0 = g4[go0], gn1 = g4[go1];

  for (int t = 0; t < T_; t++) {
    const float gc0 = gn0, gc1 = gn1;
    if (t+1 < T_) {
      gn0 = g4[go0 + (long)(t+1)*D_];
      gn1 = g4[go1 + (long)(t+1)*D_];
    }
    float r0 = gc0, r1 = gc1;
#pragma unroll
    for (int d4 = 0; d4 < 16; d4++) {
      const float4 hv = *(const float4*)(&hlds[d4*4]);
      r0 += w0[4*d4]*hv.x + w0[4*d4+1]*hv.y + w0[4*d4+2]*hv.z + w0[4*d4+3]*hv.w;
      r1 += w1[4*d4]*hv.x + w1[4*d4+1]*hv.y + w1[4*d4+2]*hv.z + w1[4*d4+3]*hv.w;
    }
    rec[gp*2][e] = r0;
    rec[gp*2+1][e] = r1;
    __syncthreads();
    if (tid < 64) {
      const float it = rec[0][e], ft = rec[1][e];
      const float zt = tanhf(rec[2][e]);
      const float ot = 1.f/(1.f+expf(-rec[3][e]));
      const float mn = fmaxf(ft + m, it);
      const float ig = expf(it - mn);
      const float fg = expf(ft + m - mn);
      c = fg*c + ig*zt;
      n = fg*n + ig;
      m = mn;
      const float hn = ot*c/fmaxf(n, 1e-6f);
      hlds[e] = hn;
      hs[(long)(b*T_+t)*D_ + hd*64 + e] = hn;
    }
    __syncthreads();
  }
}

// ---------------- sLSTM scan (fallback, reads raw Rg) ----------------
__global__ __launch_bounds__(256) void slstm_scan(
    const float* __restrict__ g4, const void* __restrict__ Rg, long offR,
    float* __restrict__ hs, const int* __restrict__ dflag)
{
  const int isbf = *dflag;
  const int blk = blockIdx.x;
  const int b = blk >> 3, hd = blk & 7;
  const int tid = threadIdx.x;
  const int g = tid >> 6, e = tid & 63;
  float w[64];
  {
    const long wp = offR + ((long)(g*NH_ + hd)*64)*64 + e;
#pragma unroll
    for (int d = 0; d < 64; d++) w[d] = ldin(Rg, wp + d*64, isbf);
  }
  __shared__ float hlds[64];
  __shared__ float rec[4][64];
  if (tid < 64) hlds[tid] = 0.f;
  float c = 0.f, n = 0.f, m = 0.f;
  __syncthreads();
  const long gate_base = (long)(b*T_)*D_ + hd*64 + e;
  for (int t = 0; t < T_; t++) {
    float r = 0.f;
#pragma unroll
    for (int d4 = 0; d4 < 16; d4++) {
      const float4 hv = *(const float4*)(&hlds[d4*4]);
      r += w[4*d4]*hv.x + w[4*d4+1]*hv.y + w[4*d4+2]*hv.z + w[4*d4+3]*hv.w;
    }
    r += g4[(long)g*BT_*D_ + gate_base + (long)t*D_];
    rec[g][e] = r;
    __syncthreads();
    if (tid < 64) {
      const float it = rec[0][e], ft = rec[1][e];
      const float zt = tanhf(rec[2][e]);
      const float ot = 1.f/(1.f+expf(-rec[3][e]));
      const float mn = fmaxf(ft + m, it);
      const float ig = expf(it - mn);
      const float fg = expf(ft + m - mn);
      c = fg*c + ig*zt;
      n = fg*n + ig;
      m = mn;
      const float hn = ot*c/fmaxf(n, 1e-6f);
      hlds[e] = hn;
      hs[(long)(b*T_+t)*D_ + hd*64 + e] = hn;
    }
    __syncthreads();
  }
}

// ---------------- head_norm(dh=64) * gn, accumulated into h ----------------
__global__ __launch_bounds__(64) void hn_add(
    const float* __restrict__ hs, const void* __restrict__ gn, long offG,
    float* __restrict__ h, const int* __restrict__ dflag)
{
  const int isbf = *dflag;
  const int blk = blockIdx.x;
  const int bt = blk >> 3, hd = blk & 7;
  const int e = threadIdx.x;
  const long idx = (long)bt*D_ + hd*64 + e;
  const float x = hs[idx];
  float s1 = x, s2 = x*x;
#pragma unroll
  for (int o = 32; o > 0; o >>= 1) { s1 += __shfl_xor(s1, o); s2 += __shfl_xor(s2, o); }
  const float mu = s1*(1.f/64.f);
  const float var = s2*(1.f/64.f) - mu*mu;
  const float y = (x-mu)*rsqrtf(var+EPS_)*ldin(gn, offG + hd*64+e, isbf);
  h[idx] += y;
}

// ---------------- FF gating: gelu(g)*up, written with 704 stride (zero pad) ----------------
__global__ void ffgate(const float* __restrict__ u, float* __restrict__ out)
{
  const long total = (long)BT_*FFP_;
  for (long idx = (long)blockIdx.x*256 + threadIdx.x; idx < total;
       idx += (long)gridDim.x*256) {
    const long m = idx / FFP_;
    const int j = (int)(idx % FFP_);
    float r = 0.f;
    if (j < FF_) {
      const float g = u[m*FF2_ + j];
      r = geluf(g) * u[m*FF2_ + FF_ + j];
    }
    out[idx] = r;
  }
}

// ---------------- mLSTM gate cumsum: one block per (b, head) ----------------
__global__ __launch_bounds__(256) void mlstm_cf(
    const float* __restrict__ g16, float* __restrict__ cf, float* __restrict__ logi)
{
  const int bh = blockIdx.x;
  const int b = bh >> 3, hd = bh & 7;
  const int tid = threadIdx.x;
  __shared__ float slf[T_];
  if (tid < T_) {
    const float gf = g16[(long)(b*T_+tid)*16 + 8 + hd];
    const float ls = (gf >= 0.f) ? -log1pf(expf(-gf)) : (gf - log1pf(expf(gf)));
    slf[tid] = ls;
    logi[(long)bh*T_ + tid] = g16[(long)(b*T_+tid)*16 + hd];
  }
  __syncthreads();
  if (tid == 0) {
    float a = 0.f;
    for (int t = 0; t < T_; t++) { a += slf[t]; slf[t] = a; }
  }
  __syncthreads();
  if (tid < T_) cf[(long)bh*T_ + tid] = slf[tid];
}

// ---------------- MFMA flash attention ----------------
#define QPD 136
#define VPD 72
__global__ __launch_bounds__(256) void attn_mfma(
    const float* __restrict__ q, const unsigned short* __restrict__ k,
    const unsigned short* __restrict__ v, const float* __restrict__ cf,
    const float* __restrict__ li, float* __restrict__ hatt)
{
  const int tt = blockIdx.x, bh = blockIdx.y;
  const int b = bh >> 3, hd = bh & 7;
  const int t0 = tt*64;
  const int tid = threadIdx.x;
  const int w = tid >> 6, lane = tid & 63;
  const int lr = lane & 15, lq = lane >> 4;

  __shared__ unsigned short sQ[64*QPD];
  __shared__ unsigned short sK[64*QPD];
  __shared__ unsigned short sVt[128*VPD];
  __shared__ unsigned short sS[64*VPD];
  __shared__ float scft[64], scfs[64], slis[64];

  for (int idx = tid; idx < 64*64; idx += 256){
    int r = idx >> 6, dp = idx & 63;
    int t = t0 + r;
    unsigned pk = 0;
    if (t < T_){
      const float* qp = q + ((long)(b*T_+t))*DI_ + hd*DHI_ + dp*2;
      pk = packbf(qp[0], qp[1]);
    }
    *(unsigned*)&sQ[r*QPD + dp*2] = pk;
  }
  if (tid < 64) scft[tid] = (t0+tid < T_) ? cf[(long)bh*T_ + t0+tid] : 0.f;

  float m_st[4], s_st[4], alpha_[4];
#pragma unroll
  for (int rr=0;rr<4;rr++){ m_st[rr] = -INFINITY; s_st[rr] = 0.f; }
  floatx4 accO[8];
#pragma unroll
  for (int nd=0;nd<8;nd++)
#pragma unroll
    for (int rr=0;rr<4;rr++) accO[nd][rr] = 0.f;

  for (int st = 0; st <= tt; st++){
    const int s0 = st*64;
    for (int idx = tid; idx < 64*64; idx += 256){
      int r = idx >> 6, dp = idx & 63;
      int s = s0 + r;
      unsigned pkk = 0, pkv = 0;
      if (s < T_){
        const long base = ((long)(b*T_+s))*DI_ + hd*DHI_ + dp*2;
        pkk = *(const unsigned*)&k[base];
        pkv = *(const unsigned*)&v[base];
      }
      *(unsigned*)&sK[r*QPD + dp*2] = pkk;
      sVt[(dp*2)*VPD + r]   = (unsigned short)(pkv & 0xFFFFu);
      sVt[(dp*2+1)*VPD + r] = (unsigned short)(pkv >> 16);
    }
    if (tid < 64){
      int s = s0 + tid;
      scfs[tid] = (s < T_) ? cf[(long)bh*T_ + s] : 0.f;
      slis[tid] = (s < T_) ? li[(long)bh*T_ + s] : 0.f;
    }
    __syncthreads();

    floatx4 accS[4];
#pragma unroll
    for (int ni=0;ni<4;ni++)
#pragma unroll
      for (int rr=0;rr<4;rr++) accS[ni][rr] = 0.f;
    const int qrow = w*16 + lr;
#pragma unroll
    for (int k0=0;k0<4;k0++){
      short8 a = *(const short8*)&sQ[qrow*QPD + k0*32 + lq*8];
#pragma unroll
      for (int ni=0;ni<4;ni++){
        short8 bb = *(const short8*)&sK[(ni*16+lr)*QPD + k0*32 + lq*8];
        accS[ni] = __builtin_amdgcn_mfma_f32_16x16x32_bf16(a, bb, accS[ni], 0,0,0);
      }
    }

#pragma unroll
    for (int rr=0;rr<4;rr++){
      const int tg = t0 + w*16 + lq*4 + rr;
      const float cftr = scft[w*16 + lq*4 + rr];
      float dmv[4];
      float mx = -INFINITY;
#pragma unroll
      for (int ni=0;ni<4;ni++){
        const int sg = s0 + ni*16 + lr;
        const bool valid = (tg < T_) && (sg <= tg);
        dmv[ni] = valid ? (cftr - scfs[ni*16+lr] + slis[ni*16+lr]) : -INFINITY;
        mx = fmaxf(mx, dmv[ni]);
      }
      mx = fmaxf(mx, __shfl_xor(mx, 1));
      mx = fmaxf(mx, __shfl_xor(mx, 2));
      mx = fmaxf(mx, __shfl_xor(mx, 4));
      mx = fmaxf(mx, __shfl_xor(mx, 8));
      const float mnew = fmaxf(m_st[rr], mx);
      const float al = (mnew == -INFINITY) ? 0.f : expf(m_st[rr] - mnew);
      float rs = 0.f;
#pragma unroll
      for (int ni=0;ni<4;ni++){
        const float wexp = (dmv[ni] == -INFINITY) ? 0.f : expf(dmv[ni] - mnew);
        const float pv = accS[ni][rr]*wexp;
        rs += pv;
        sS[(w*16 + lq*4 + rr)*VPD + ni*16 + lr] = f2bu(pv);
      }
      rs += __shfl_xor(rs, 1);
      rs += __shfl_xor(rs, 2);
      rs += __shfl_xor(rs, 4);
      rs += __shfl_xor(rs, 8);
      s_st[rr] = s_st[rr]*al + rs;
      m_st[rr] = mnew;
      alpha_[rr] = al;
    }

#pragma unroll
    for (int nd=0;nd<8;nd++)
#pragma unroll
      for (int rr=0;rr<4;rr++) accO[nd][rr] *= alpha_[rr];

#pragma unroll
    for (int ks=0;ks<2;ks++){
      short8 aP = *(const short8*)&sS[(w*16 + lr)*VPD + ks*32 + lq*8];
#pragma unroll
      for (int nd=0;nd<8;nd++){
        short8 bV = *(const short8*)&sVt[(nd*16+lr)*VPD + ks*32 + lq*8];
        accO[nd] = __builtin_amdgcn_mfma_f32_16x16x32_bf16(aP, bV, accO[nd], 0,0,0);
      }
    }
    __syncthreads();
  }

#pragma unroll
  for (int rr=0;rr<4;rr++){
    const int tg = t0 + w*16 + lq*4 + rr;
    if (tg >= T_) continue;
    const float inv = 1.f / fmaxf(fabsf(s_st[rr]), expf(-m_st[rr]));
    float* op = hatt + ((long)(b*T_+tg))*DI_ + hd*DHI_;
#pragma unroll
    for (int nd=0;nd<8;nd++)
      op[nd*16 + lr] = accO[nd][rr]*inv;
  }
}

// ---------------- head_norm(dh=128)*gn + skip*xc, then *silu(z) ----------------
__global__ __launch_bounds__(128) void hn_mlstm(
    const float* __restrict__ hatt, const void* __restrict__ gn, long offG,
    const void* __restrict__ skip, long offSk, const float* __restrict__ xc,
    const float* __restrict__ u, float* __restrict__ gin,
    const int* __restrict__ dflag)
{
  const int isbf = *dflag;
  const int blk = blockIdx.x;
  const int bt = blk >> 3, hd = blk & 7;
  const int e = threadIdx.x;
  const int j = hd*DHI_ + e;
  const long idx = (long)bt*DI_ + j;
  const float x = hatt[idx];
  __shared__ float r1[128], r2[128];
  r1[e]=x; r2[e]=x*x; __syncthreads();
  for (int o=64;o>0;o>>=1){ if(e<o){r1[e]+=r1[e+o]; r2[e]+=r2[e+o];} __syncthreads(); }
  const float mu = r1[0]*(1.f/128.f);
  const float var = r2[0]*(1.f/128.f)-mu*mu;
  const float y = (x-mu)*rsqrtf(var+EPS_)*ldin(gn, offG+j, isbf) + ldin(skip, offSk+j, isbf)*xc[idx];
  const float z = u[(long)bt*2048 + DI_ + j];
  gin[idx] = y * siluf(z);
}

// ---------------- final transpose to output ----------------
__global__ void out_transpose(const float* __restrict__ hp, void* __restrict__ out,
                              const int* __restrict__ dflag)
{
  const int isbf = *dflag;
  const int tid = threadIdx.x;
  if (tid < B_*6) {
    const int b = tid / 6, hd = tid % 6;
    const float v = hp[hd*B_ + b];
    if (isbf) ((bf16*)out)[tid] = __float2bfloat16(v);
    else      ((float*)out)[tid] = v;
  }
}

extern "C" void kernel_launch(void* const* d_in, const int* in_sizes, int n_in,
                              void* d_out, int out_size, void* d_ws, size_t ws_size,
                              hipStream_t stream)
{
  (void)in_sizes; (void)n_in; (void)out_size;
  const void* x        = d_in[0];
  const void* w_in     = d_in[1];
  const void* b_in     = d_in[2];
  const void* ln_in_s  = d_in[3];
  const void* ln_in_b  = d_in[4];
  const void* s_ln_s   = d_in[5];
  const void* s_ln_b   = d_in[6];
  const void* s_conv_w = d_in[7];
  const void* s_conv_b = d_in[8];
  const void* s_wg     = d_in[9];
  const void* s_rg     = d_in[10];
  const void* s_bg     = d_in[11];
  const void* s_gn     = d_in[12];
  const void* s_ffln_s = d_in[13];
  const void* s_ffln_b = d_in[14];
  const void* s_ff_w1  = d_in[15];
  const void* s_ff_w2  = d_in[16];
  const void* m_ln_s   = d_in[17];
  const void* m_ln_b   = d_in[18];
  const void* m_w_up   = d_in[19];
  const void* m_conv_w = d_in[20];
  const void* m_conv_b = d_in[21];
  const void* m_wq     = d_in[22];
  const void* m_wk     = d_in[23];
  const void* m_wv     = d_in[24];
  const void* m_w_if   = d_in[25];
  const void* m_b_if   = d_in[26];
  const void* m_skip   = d_in[27];
  const void* m_gn     = d_in[28];
  const void* m_w_down = d_in[29];
  const void* post_ln_s= d_in[30];
  const void* post_ln_b= d_in[31];
  const void* hw1      = d_in[32];
  const void* hb1      = d_in[33];
  const void* hw2      = d_in[34];
  const void* hb2      = d_in[35];
  const void* hw3      = d_in[36];
  const void* hb3      = d_in[37];

  float* W   = (float*)d_ws;
  float* h   = W;                           // BT*D
  float* xn  = W + 4128768L;                // BT*D
  float* xc  = W + 8257536L;                // BT*DI
  float* u   = W + 16515072L;               // 4*BT*D
  float* q   = W + 33030144L;               // BT*DI fp32 (hs / ffg(704) / hatt / gin)
  unsigned short* kk_ = (unsigned short*)(W + 41287680L); // BT*DI bf16
  unsigned short* vv_ = (unsigned short*)(W + 45416448L); // BT*DI bf16
  float* g16 = W + 49545216L;               // BT*16
  float* cfb = W + 49674240L;               // B*NH*T
  float* lib = W + 49738752L;               // B*NH*T
  float* last= W + 49803264L;               // 32*512
  float* ha1 = W + 49819648L;               // 6*32*256
  float* ha2 = W + 49868800L;               // 6*32*128
  float* hp  = W + 49893376L;               // 6*32 (pad)
  int*   dfl = (int*)(W + 49893568L);
  float* wsRg = W + 49893632L;              // 4 layers x 4x8x64x64 fp32 = 524288 floats

  // bf16 weight planes (hi, lo), each PLANE ushorts, k-contiguous [N][K]
  const long PLANE = 14327808L;
  unsigned short* wtHi = (unsigned short*)(W + 50417920L);
  unsigned short* wtLo = wtHi + PLANE;
  const long oWg=0, oF1=4194304L, oF2=6987776L, oUp=8429568L;
  const long oQ=11575296L, oK=11968512L, oV=12361728L, oDn=12754944L;

  const size_t needFull = (size_t)(50417920L + PLANE)*4;            // ~259.0 MB
  const size_t needMid  = (size_t)(50417920L + PLANE/2)*4 + PLANE;  // tier1: hi plane only
  const int tier = (ws_size >= needFull) ? 2 : ((ws_size >= needMid) ? 1 : 0);
  const int spB = (tier == 2) ? 1 : 0;
  unsigned short* loArg = (tier == 2) ? wtLo : nullptr;

  const float kscale = 0.08838834764831845f; // 1/sqrt(128)

  detect_dtype<<<1, 64, 0, stream>>>((const unsigned*)ln_in_s, dfl);

  if (tier >= 1) {
    rg_prep<<<128, 256, 0, stream>>>(s_rg, wsRg, dfl);
    wt_transpose2<<<dim3(16,16,16),256,0,stream>>>(s_wg, 0, 262144L, 512, 512, 512,
        wtHi+oWg, loArg?loArg+oWg:nullptr, 262144L, dfl);
    wt_transpose2<<<dim3(43,16,4),256,0,stream>>>(s_ff_w1, 0, 698368L, 512, 1364, 512,
        wtHi+oF1, loArg?loArg+oF1:nullptr, 698368L, dfl);
    wt_transpose2<<<dim3(16,22,4),256,0,stream>>>(s_ff_w2, 0, 349184L, 682, 512, 704,
        wtHi+oF2, loArg?loArg+oF2:nullptr, 360448L, dfl);
    wt_transpose2<<<dim3(64,16,3),256,0,stream>>>(m_w_up, 0, 1048576L, 512, 2048, 512,
        wtHi+oUp, loArg?loArg+oUp:nullptr, 1048576L, dfl);
    wt_transpose2<<<dim3(4,4,24),256,0,stream>>>(m_wq, 0, 16384L, 128, 128, 128,
        wtHi+oQ, loArg?loArg+oQ:nullptr, 16384L, dfl);
    wt_transpose2<<<dim3(4,4,24),256,0,stream>>>(m_wk, 0, 16384L, 128, 128, 128,
        wtHi+oK, loArg?loArg+oK:nullptr, 16384L, dfl);
    wt_transpose2<<<dim3(4,4,24),256,0,stream>>>(m_wv, 0, 16384L, 128, 128, 128,
        wtHi+oV, loArg?loArg+oV:nullptr, 16384L, dfl);
    wt_transpose2<<<dim3(16,32,3),256,0,stream>>>(m_w_down, 0, 524288L, 1024, 512, 1024,
        wtHi+oDn, loArg?loArg+oDn:nullptr, 524288L, dfl);
  }

  ln_proj<<<BT_, 256, 0, stream>>>(x, w_in, b_in, ln_in_s, ln_in_b, h, dfl);

  int si = 0, mi = 0;
  for (int blk = 0; blk < 7; blk++) {
    if ((blk & 1) == 0) {
      // ---- sLSTM block ----
      ln_rows<<<BT_,256,0,stream>>>(h, 512L, s_ln_s, (long)si*512, s_ln_b, (long)si*512, xn, dfl);
      {
        long tot = (long)BT_*512; int g = (int)((tot+255)/256);
        conv_silu<<<g,256,0,stream>>>(xn, 512, s_conv_w, (long)si*4*512, s_conv_b, (long)si*512, xc, 512, dfl);
      }
      if (tier >= 1) {
        gemm_split<<<dim3(8,126,4),256,0,stream>>>(xc, xn, 2, 0L,
            wtHi+oWg+(long)si*4*262144L, wtLo+oWg+(long)si*4*262144L,
            s_bg, (long)si*4*512, u,
            512, 512, 512, 512, 262144L, (long)BT_*512, 512L, 1.f, 1, spB, dfl);
      } else {
        for (int g = 0; g < 4; g++) {
          const float* Ain = (g < 2) ? xc : xn;
          gemm_f32b<<<dim3(8,126,1),256,0,stream>>>(Ain, s_wg, ((long)(si*4+g))*512*512,
              s_bg, (long)(si*4+g)*512, u + (long)g*BT_*512,
              BT_, 512, 512, 512, 512, 512, 0,0,0,0, 1.f, 1, dfl);
        }
      }
      if (tier >= 1)
        slstm_scan2<<<256,128,0,stream>>>(u, wsRg + (long)si*131072L, q /*hs*/);
      else
        slstm_scan<<<256,256,0,stream>>>(u, s_rg, (long)si*4*8*64*64, q /*hs*/, dfl);
      hn_add<<<BT_*8,64,0,stream>>>(q, s_gn, (long)si*512, h, dfl);
      // ---- FF block ----
      ln_rows<<<BT_,256,0,stream>>>(h, 512L, s_ffln_s, (long)si*512, s_ffln_b, (long)si*512, xn, dfl);
      if (tier >= 1)
        gemm_split<<<dim3(22,126,1),256,0,stream>>>(xn, xn, 9, 0L,
            wtHi+oF1+(long)si*698368L, wtLo+oF1+(long)si*698368L, nullptr, 0,
            u, 1364, 512, 512, 1364, 0,0,0, 1.f, 0, spB, dfl);
      else
        gemm_f32b<<<dim3(22,126,1),256,0,stream>>>(xn, s_ff_w1, (long)si*512*1364, nullptr, 0,
            u, BT_, 1364, 512, 512, 1364, 1364, 0,0,0,0, 1.f, 0, dfl);
      {
        long tot = (long)BT_*FFP_; int g = (int)((tot+255)/256);
        ffgate<<<g,256,0,stream>>>(u, q /*ffg, stride 704*/);
      }
      if (tier >= 1)
        gemm_split<<<dim3(8,126,1),256,0,stream>>>(q, q, 9, 0L,
            wtHi+oF2+(long)si*360448L, wtLo+oF2+(long)si*360448L, nullptr, 0,
            h, 512, 704, 704, 512, 0,0,0, 1.f, 2, spB, dfl);
      else
        gemm_f32b<<<dim3(8,126,1),256,0,stream>>>(q, s_ff_w2, (long)si*682*512, nullptr, 0,
            h, BT_, 512, 682, 704, 512, 512, 0,0,0,0, 1.f, 2, dfl);
      si++;
    } else {
      // ---- mLSTM block ----
      ln_rows<<<BT_,256,0,stream>>>(h, 512L, m_ln_s, (long)mi*512, m_ln_b, (long)mi*512, xn, dfl);
      if (tier >= 1)
        gemm_split<<<dim3(32,126,1),256,0,stream>>>(xn, xn, 9, 0L,
            wtHi+oUp+(long)mi*1048576L, wtLo+oUp+(long)mi*1048576L, nullptr, 0,
            u, 2048, 512, 512, 2048, 0,0,0, 1.f, 0, spB, dfl);
      else
        gemm_f32b<<<dim3(32,126,1),256,0,stream>>>(xn, m_w_up, (long)mi*512*2048, nullptr, 0,
            u, BT_, 2048, 512, 512, 2048, 2048, 0,0,0,0, 1.f, 0, dfl);
      {
        long tot = (long)BT_*1024; int g = (int)((tot+255)/256);
        conv_silu<<<g,256,0,stream>>>(u, 2048, m_conv_w, (long)mi*4*1024, m_conv_b, (long)mi*1024, xc, 1024, dfl);
      }
      if (tier >= 1) {
        gemm_split<<<dim3(2,126,8),256,0,stream>>>(xc, xc, 9, 128L,
            wtHi+oQ+(long)mi*131072L, wtLo+oQ+(long)mi*131072L, nullptr, 0,
            q, 128, 128, 1024, 1024, 16384L, 128L, 0, 1.f, 0, spB, dfl);
        gemm_split<<<dim3(2,126,8),256,0,stream>>>(xc, xc, 9, 128L,
            wtHi+oK+(long)mi*131072L, wtLo+oK+(long)mi*131072L, nullptr, 0,
            (float*)kk_, 128, 128, 1024, 1024, 16384L, 128L, 0, kscale, 8, spB, dfl);
        gemm_split<<<dim3(2,126,8),256,0,stream>>>(u, u, 9, 128L,
            wtHi+oV+(long)mi*131072L, wtLo+oV+(long)mi*131072L, nullptr, 0,
            (float*)vv_, 128, 128, 2048, 1024, 16384L, 128L, 0, 1.f, 8, spB, dfl);
      } else {
        gemm_f32b<<<dim3(2,126,8),256,0,stream>>>(xc, m_wq, (long)mi*8*128*128, nullptr, 0,
            q, BT_, 128, 128, 1024, 128, 1024, 128, 16384, 128, 0, 1.f, 0, dfl);
        gemm_f32b<<<dim3(2,126,8),256,0,stream>>>(xc, m_wk, (long)mi*8*128*128, nullptr, 0,
            (float*)kk_, BT_, 128, 128, 1024, 128, 1024, 128, 16384, 128, 0, kscale, 8, dfl);
        gemm_f32b<<<dim3(2,126,8),256,0,stream>>>(u, m_wv, (long)mi*8*128*128, nullptr, 0,
            (float*)vv_, BT_, 128, 128, 2048, 128, 1024, 128, 16384, 128, 0, 1.f, 8, dfl);
      }
      gemm_f32b<<<dim3(1,126,1),256,0,stream>>>(xc, m_w_if, (long)mi*1024*16, m_b_if, (long)mi*16,
            g16, BT_, 16, 1024, 1024, 16, 16, 0,0,0,0, 1.f, 1, dfl);
      mlstm_cf<<<256,256,0,stream>>>(g16, cfb, lib);
      attn_mfma<<<dim3(4,256),256,0,stream>>>(q, kk_, vv_, cfb, lib, q /*hatt in-place*/);
      hn_mlstm<<<BT_*8,128,0,stream>>>(q, m_gn, (long)mi*1024, m_skip, (long)mi*1024, xc, u, q, dfl);
      if (tier >= 1)
        gemm_split<<<dim3(8,126,1),256,0,stream>>>(q, q, 9, 0L,
            wtHi+oDn+(long)mi*524288L, wtLo+oDn+(long)mi*524288L, nullptr, 0,
            h, 512, 1024, 1024, 512, 0,0,0, 1.f, 2, spB, dfl);
      else
        gemm_f32b<<<dim3(8,126,1),256,0,stream>>>(q, m_w_down, (long)mi*1024*512, nullptr, 0,
            h, BT_, 512, 1024, 1024, 512, 512, 0,0,0,0, 1.f, 2, dfl);
      mi++;
    }
  }

  // post-LN on last timestep rows only
  ln_rows<<<B_,256,0,stream>>>(h + (long)(T_-1)*512, (long)T_*512, post_ln_s, 0, post_ln_b, 0, last, dfl);

  // 6 prediction heads, batched over grid.z (tiny; SIMT fp32)
  gemm_f32b<<<dim3(4,1,6),256,0,stream>>>(last, hw1, 0, hb1, 0, ha1, 32, 256, 512, 512, 256, 256,
        0, 512L*256, 32L*256, 256, 1.f, 1|4, dfl);
  gemm_f32b<<<dim3(2,1,6),256,0,stream>>>(ha1, hw2, 0, hb2, 0, ha2, 32, 128, 256, 256, 128, 128,
        32L*256, 256L*128, 32L*128, 128, 1.f, 1|4, dfl);
  gemm_f32b<<<dim3(1,1,6),256,0,stream>>>(ha2, hw3, 0, hb3, 0, hp, 32, 1, 128, 128, 1, 1,
        32L*128, 128L, 32L, 1, 1.f, 1, dfl);
  out_transpose<<<1,256,0,stream>>>(hp, d_out, dfl);
}

// Round 8
// 4056.721 us; speedup vs baseline: 1.0503x; 1.0503x over previous
//
#include <hip/hip_runtime.h>
#include <hip/hip_bf16.h>
#include <cmath>

typedef __hip_bfloat16 bf16;

#define B_   32
#define T_   252
#define F_   8
#define D_   512
#define NH_  8
#define DH_  64
#define DI_  1024
#define DHI_ 128
#define FF_  682
#define FF2_ 1364
#define FFP_ 704
#define BT_  (B_*T_)
#define EPS_ 1e-5f

typedef __attribute__((ext_vector_type(8))) short short8;
typedef __attribute__((ext_vector_type(4))) float floatx4;

__device__ __forceinline__ float b2f(bf16 v){ return __bfloat162float(v); }
__device__ __forceinline__ float siluf(float x){ return x/(1.f+expf(-x)); }
__device__ __forceinline__ float geluf(float x){
  float x3 = x*x*x;
  return 0.5f*x*(1.f+tanhf(0.7978845608028654f*(x+0.044715f*x3)));
}
__device__ __forceinline__ float ldin(const void* p, long i, int isbf){
  return isbf ? __bfloat162float(((const bf16*)p)[i]) : ((const float*)p)[i];
}
__device__ __forceinline__ unsigned short f2bu(float f){
  bf16 h = __float2bfloat16(f);
  return *(reinterpret_cast<unsigned short*>(&h));
}
__device__ __forceinline__ void split2(float v, unsigned short& h, unsigned short& l){
  bf16 hb = __float2bfloat16(v);
  h = *(reinterpret_cast<unsigned short*>(&hb));
  float r = v - __bfloat162float(hb);
  bf16 lb = __float2bfloat16(r);
  l = *(reinterpret_cast<unsigned short*>(&lb));
}
__device__ __forceinline__ unsigned packbf(float x, float y){
  return (unsigned)f2bu(x) | ((unsigned)f2bu(y) << 16);
}

__global__ void detect_dtype(const unsigned* __restrict__ probe, int* __restrict__ flag)
{
  if (threadIdx.x == 0) *flag = (*probe == 0x3F803F80u) ? 1 : 0;
}

// ---- sLSTM recurrent weight prep: Rg [si][g][hd][d][e] -> fp32 [(si*4+g)*8+hd][e][d] ----
__global__ __launch_bounds__(256) void rg_prep(
    const void* __restrict__ Rg, float* __restrict__ out, const int* __restrict__ dflag)
{
  const int isbf = *dflag;
  const int c = blockIdx.x;          // 0..127 = (si*4+g)*8+hd
  const long base = (long)c*4096;
  __shared__ float tl[64][65];
  const int col = threadIdx.x & 63, r4 = threadIdx.x >> 6;
#pragma unroll
  for (int i=0;i<16;i++){
    int d = i*4 + r4;
    tl[d][col] = ldin(Rg, base + (long)d*64 + col, isbf);
  }
  __syncthreads();
#pragma unroll
  for (int i=0;i<16;i++){
    int e = i*4 + r4;
    out[base + (long)e*64 + col] = tl[col][e];
  }
}

// ---- weight transpose + hi/lo bf16 split: in [K][N] -> planes [N][outK] (outK>=K zero-pad) ----
__global__ __launch_bounds__(256) void wt_transpose2(
    const void* __restrict__ in, long inOff, long inStride, int K, int N, int outK,
    unsigned short* __restrict__ outHi, unsigned short* __restrict__ outLo,
    long outStride, const int* __restrict__ dflag)
{
  const int isbf = *dflag;
  const int bz = blockIdx.z;
  const long base = inOff + (long)bz*inStride;
  unsigned short* oh = outHi + (long)bz*outStride;
  unsigned short* ol = outLo ? outLo + (long)bz*outStride : nullptr;
  __shared__ float tile[32][33];
  const int k0 = blockIdx.y*32, n0 = blockIdx.x*32;
  const int tn = threadIdx.x & 31, tk = threadIdx.x >> 5;
#pragma unroll
  for (int i=0;i<4;i++){
    int kk = tk + i*8;
    float v = 0.f;
    if (k0+kk < K && n0+tn < N) v = ldin(in, base + (long)(k0+kk)*N + n0+tn, isbf);
    tile[kk][tn] = v;
  }
  __syncthreads();
#pragma unroll
  for (int i=0;i<4;i++){
    int nn = tk + i*8;
    if (n0+nn < N && k0+tn < outK){
      unsigned short h, l;
      split2(tile[tn][nn], h, l);
      oh[(long)(n0+nn)*outK + k0+tn] = h;
      if (ol) ol[(long)(n0+nn)*outK + k0+tn] = l;
    }
  }
}

// ---- split-bf16 MFMA GEMM: C = alpha*(A@B) [+bias] [+C] ----
// flags: 1=bias, 2=accumulate, 8=store C as packed bf16 (ushort)
__global__ __launch_bounds__(256) void gemm_split(
    const float* __restrict__ A0, const float* __restrict__ A1, int zSplit, long strideA,
    const unsigned short* __restrict__ Bhi, const unsigned short* __restrict__ Blo,
    const void* __restrict__ bias, long offBias, float* __restrict__ C,
    int N, int K, int lda, int ldc,
    long strideBT, long strideC, long strideBias,
    float alpha, int flags, int splitB, const int* __restrict__ dflag)
{
  const int isbf = *dflag;
  const int bz = blockIdx.z;
  const float* A = ((bz < zSplit) ? A0 : A1) + (long)bz*strideA;
  const unsigned short* bhp = Bhi + (long)bz*strideBT;
  const unsigned short* blp = Blo + (long)bz*strideBT;
  const long cBase = (long)bz*strideC;
  const long bBias = offBias + (long)bz*strideBias;

  __shared__ unsigned short aH[64*72], aL[64*72], bH[64*72], bL[64*72];
  const int tid = threadIdx.x;
  const int wid = tid >> 6, lane = tid & 63;
  const int wm = (wid >> 1)*32, wn = (wid & 1)*32;
  const int m0 = blockIdx.y*64, n0 = blockIdx.x*64;
  const int lr = lane & 15, lq = lane >> 4;

  floatx4 acc[2][2];
#pragma unroll
  for (int mi=0;mi<2;mi++)
#pragma unroll
    for (int ni=0;ni<2;ni++)
#pragma unroll
      for (int r=0;r<4;r++) acc[mi][ni][r] = 0.f;

  const int sRow = tid >> 2;
  const int sSeg = (tid & 3)*16;

  for (int k0 = 0; k0 < K; k0 += 64) {
    {
      const float* ap = A + (long)(m0 + sRow)*lda + k0 + sSeg;
#pragma unroll
      for (int c=0;c<4;c++){
        const float4 v = *(const float4*)(ap + c*4);
        unsigned short h0,h1,h2,h3,l0,l1,l2,l3;
        split2(v.x,h0,l0); split2(v.y,h1,l1); split2(v.z,h2,l2); split2(v.w,h3,l3);
        uint2 ph, pl;
        ph.x = (unsigned)h0 | ((unsigned)h1<<16); ph.y = (unsigned)h2 | ((unsigned)h3<<16);
        pl.x = (unsigned)l0 | ((unsigned)l1<<16); pl.y = (unsigned)l2 | ((unsigned)l3<<16);
        *(uint2*)&aH[sRow*72 + sSeg + c*4] = ph;
        *(uint2*)&aL[sRow*72 + sSeg + c*4] = pl;
      }
    }
    {
      const int gn = n0 + sRow;
      const bool nv = gn < N;
      const long bo = (long)gn*K + k0 + sSeg;
      uint4 z4; z4.x=z4.y=z4.z=z4.w=0;
      uint4 h0 = nv ? *(const uint4*)(bhp + bo)     : z4;
      uint4 h1 = nv ? *(const uint4*)(bhp + bo + 8) : z4;
      *(uint4*)&bH[sRow*72 + sSeg]     = h0;
      *(uint4*)&bH[sRow*72 + sSeg + 8] = h1;
      if (splitB){
        uint4 l0_ = nv ? *(const uint4*)(blp + bo)     : z4;
        uint4 l1_ = nv ? *(const uint4*)(blp + bo + 8) : z4;
        *(uint4*)&bL[sRow*72 + sSeg]     = l0_;
        *(uint4*)&bL[sRow*72 + sSeg + 8] = l1_;
      }
    }
    __syncthreads();

#pragma unroll
    for (int ks=0;ks<2;ks++){
      short8 ah[2], al[2], bh_[2], bl_[2];
#pragma unroll
      for (int mi=0;mi<2;mi++){
        ah[mi] = *(const short8*)&aH[(wm+mi*16+lr)*72 + ks*32 + lq*8];
        al[mi] = *(const short8*)&aL[(wm+mi*16+lr)*72 + ks*32 + lq*8];
      }
#pragma unroll
      for (int ni=0;ni<2;ni++){
        bh_[ni] = *(const short8*)&bH[(wn+ni*16+lr)*72 + ks*32 + lq*8];
        if (splitB) bl_[ni] = *(const short8*)&bL[(wn+ni*16+lr)*72 + ks*32 + lq*8];
      }
#pragma unroll
      for (int mi=0;mi<2;mi++)
#pragma unroll
        for (int ni=0;ni<2;ni++){
          acc[mi][ni] = __builtin_amdgcn_mfma_f32_16x16x32_bf16(al[mi], bh_[ni], acc[mi][ni], 0,0,0);
          if (splitB)
            acc[mi][ni] = __builtin_amdgcn_mfma_f32_16x16x32_bf16(ah[mi], bl_[ni], acc[mi][ni], 0,0,0);
          acc[mi][ni] = __builtin_amdgcn_mfma_f32_16x16x32_bf16(ah[mi], bh_[ni], acc[mi][ni], 0,0,0);
        }
    }
    __syncthreads();
  }

#pragma unroll
  for (int mi=0;mi<2;mi++){
#pragma unroll
    for (int ni=0;ni<2;ni++){
      const int gn = n0 + wn + ni*16 + lr;
      if (gn >= N) continue;
      const float bv = (flags & 1) ? ldin(bias, bBias + gn, isbf) : 0.f;
#pragma unroll
      for (int rr=0;rr<4;rr++){
        const int gm = m0 + wm + mi*16 + lq*4 + rr;
        float vv = acc[mi][ni][rr]*alpha + bv;
        const long idx = cBase + (long)gm*ldc + gn;
        if (flags & 8) {
          ((unsigned short*)C)[idx] = f2bu(vv);
        } else {
          if (flags & 2) vv += C[idx];
          C[idx] = vv;
        }
      }
    }
  }
}

// ---------------- input projection + layernorm ----------------
__global__ __launch_bounds__(256) void ln_proj(
    const void* __restrict__ x, const void* __restrict__ w,
    const void* __restrict__ bb, const void* __restrict__ s,
    const void* __restrict__ b, float* __restrict__ out,
    const int* __restrict__ dflag)
{
  const int isbf = *dflag;
  const int r = blockIdx.x;
  const int tid = threadIdx.x;
  float xr[8];
#pragma unroll
  for (int f = 0; f < 8; f++) xr[f] = ldin(x, (long)r*8+f, isbf);
  float vv[2];
#pragma unroll
  for (int i2 = 0; i2 < 2; i2++) {
    const int j = tid + i2*256;
    float a = ldin(bb, j, isbf);
#pragma unroll
    for (int f = 0; f < 8; f++) a += xr[f]*ldin(w, f*512+j, isbf);
    vv[i2] = a;
  }
  __shared__ float r1[256], r2[256];
  r1[tid] = vv[0]+vv[1]; r2[tid] = vv[0]*vv[0]+vv[1]*vv[1];
  __syncthreads();
  for (int o = 128; o > 0; o >>= 1) {
    if (tid < o) { r1[tid]+=r1[tid+o]; r2[tid]+=r2[tid+o]; }
    __syncthreads();
  }
  const float mu = r1[0]*(1.f/512.f);
  const float var = r2[0]*(1.f/512.f)-mu*mu;
  const float rstd = rsqrtf(var+EPS_);
  float* orow = out + (long)r*512;
#pragma unroll
  for (int i2 = 0; i2 < 2; i2++) {
    const int j = tid + i2*256;
    orow[j] = (vv[i2]-mu)*rstd*ldin(s, j, isbf) + ldin(b, j, isbf);
  }
}

// ---------------- layernorm over 512-elem rows ----------------
__global__ __launch_bounds__(256) void ln_rows(
    const float* __restrict__ in, long rowStride,
    const void* __restrict__ s, long offS,
    const void* __restrict__ b, long offB,
    float* __restrict__ out, const int* __restrict__ dflag)
{
  const int isbf = *dflag;
  const long r = blockIdx.x;
  const int tid = threadIdx.x;
  const float* xr = in + r*rowStride;
  const float v0 = xr[tid], v1 = xr[tid+256];
  __shared__ float r1[256], r2[256];
  r1[tid] = v0+v1; r2[tid] = v0*v0+v1*v1;
  __syncthreads();
  for (int o = 128; o > 0; o >>= 1) {
    if (tid < o) { r1[tid]+=r1[tid+o]; r2[tid]+=r2[tid+o]; }
    __syncthreads();
  }
  const float mu = r1[0]*(1.f/512.f);
  const float var = r2[0]*(1.f/512.f)-mu*mu;
  const float rstd = rsqrtf(var+EPS_);
  float* orow = out + r*(long)D_;
  orow[tid]     = (v0-mu)*rstd*ldin(s, offS+tid, isbf)     + ldin(b, offB+tid, isbf);
  orow[tid+256] = (v1-mu)*rstd*ldin(s, offS+tid+256, isbf) + ldin(b, offB+tid+256, isbf);
}

// ---------------- causal conv(K=4) + silu ----------------
__global__ void conv_silu(const float* __restrict__ in, int inStride,
                          const void* __restrict__ w, long offW,
                          const void* __restrict__ bias, long offBias,
                          float* __restrict__ out, int Dc,
                          const int* __restrict__ dflag)
{
  const int isbf = *dflag;
  const long total = (long)BT_ * Dc;
  for (long idx = (long)blockIdx.x*256 + threadIdx.x; idx < total;
       idx += (long)gridDim.x*256) {
    const int d = (int)(idx % Dc);
    const long bt = idx / Dc;
    const int b = (int)(bt / T_), t = (int)(bt % T_);
    float a = ldin(bias, offBias + d, isbf);
#pragma unroll
    for (int kk = 0; kk < 4; kk++) {
      const int ts = t - 3 + kk;
      if (ts >= 0) a += ldin(w, offW + kk*Dc + d, isbf) * in[((long)(b*T_+ts))*inStride + d];
    }
    out[idx] = siluf(a);
  }
}

// ---------------- fallback SIMT GEMM ----------------
__global__ __launch_bounds__(256) void gemm_f32b(
    const float* __restrict__ A, const void* __restrict__ Bw, long offB,
    const void* __restrict__ bias, long offBias, float* __restrict__ C,
    int M, int N, int K, int lda, int ldb, int ldc,
    long strideA, long strideB, long strideC, long strideBias,
    float alpha, int flags, const int* __restrict__ dflag)
{
  const int isbf = *dflag;
  const int bz = blockIdx.z;
  A  += (long)bz * strideA;
  const long bB = offB + (long)bz * strideB;
  const long cBase = (long)bz * strideC;
  const long bBias = offBias + (long)bz * strideBias;
  __shared__ float sA[16][68];
  __shared__ float sB[16][64];
  const int tid = threadIdx.x;
  const int tx = tid & 15, ty = tid >> 4;
  const int m0 = blockIdx.y * 64, n0 = blockIdx.x * 64;
  float acc[4][4];
#pragma unroll
  for (int i=0;i<4;i++)
#pragma unroll
    for (int j=0;j<4;j++) acc[i][j]=0.f;

  for (int k0 = 0; k0 < K; k0 += 16) {
#pragma unroll
    for (int r = 0; r < 4; r++) {
      int lin = tid + r*256;
      int kk = lin & 15, m = lin >> 4;
      int gm = m0 + m, gk = k0 + kk;
      sA[kk][m] = (gm < M && gk < K) ? A[(long)gm*lda + gk] : 0.f;
    }
#pragma unroll
    for (int r = 0; r < 4; r++) {
      int lin = tid + r*256;
      int nn = lin & 63, kk = lin >> 6;
      int gn = n0 + nn, gk = k0 + kk;
      sB[kk][nn] = (gn < N && gk < K) ? ldin(Bw, bB + (long)gk*ldb + gn, isbf) : 0.f;
    }
    __syncthreads();
#pragma unroll
    for (int kk = 0; kk < 16; kk++) {
      const float4 a4 = *(const float4*)(&sA[kk][ty*4]);
      const float4 b4 = *(const float4*)(&sB[kk][tx*4]);
      float av[4] = {a4.x, a4.y, a4.z, a4.w};
      float bv[4] = {b4.x, b4.y, b4.z, b4.w};
#pragma unroll
      for (int i=0;i<4;i++)
#pragma unroll
        for (int j=0;j<4;j++) acc[i][j] += av[i]*bv[j];
    }
    __syncthreads();
  }
#pragma unroll
  for (int i=0;i<4;i++) {
    const int gm = m0 + ty*4 + i;
    if (gm >= M) continue;
#pragma unroll
    for (int j=0;j<4;j++) {
      const int gn = n0 + tx*4 + j;
      if (gn >= N) continue;
      float vv = acc[i][j]*alpha;
      if (flags & 1) vv += ldin(bias, bBias + gn, isbf);
      if (flags & 4) vv = geluf(vv);
      const long idx = cBase + (long)gm*ldc + gn;
      if (flags & 8) {
        ((unsigned short*)C)[idx] = f2bu(vv);
      } else {
        if (flags & 2) vv += C[idx];
        C[idx] = vv;
      }
    }
  }
}

// ---------------- sLSTM scan v3: 256 threads, 1 gate/thread, fp32 weights in regs ----------------
// weights pre-transposed fp32 [(g*8+hd)][e][d] (d contiguous); tanh/sigmoid on owning waves
__global__ __launch_bounds__(256) void slstm_scan3(
    const float* __restrict__ g4, const float* __restrict__ wR,
    float* __restrict__ hs)
{
  const int blk = blockIdx.x;
  const int b = blk >> 3, hd = blk & 7;
  const int tid = threadIdx.x;
  const int g = tid >> 6, e = tid & 63;

  float4 w[16];
  {
    const float* p = wR + (((long)g*8 + hd)*64 + e)*64;
#pragma unroll
    for (int d4 = 0; d4 < 16; d4++) w[d4] = *(const float4*)(p + d4*4);
  }

  __shared__ float hlds[64];
  __shared__ float rec[4][64];
  if (tid < 64) hlds[tid] = 0.f;
  float c = 0.f, n = 0.f, m = 0.f;
  __syncthreads();

  const long gbase = (long)g*BT_*D_ + (long)(b*T_)*D_ + hd*64 + e;
  float gnext = g4[gbase];

  for (int t = 0; t < T_; t++) {
    const float gc = gnext;
    if (t+1 < T_) gnext = g4[gbase + (long)(t+1)*D_];
    float r = gc;
#pragma unroll
    for (int d4 = 0; d4 < 16; d4++) {
      const float4 hv = *(const float4*)(&hlds[d4*4]);
      r += w[d4].x*hv.x + w[d4].y*hv.y + w[d4].z*hv.z + w[d4].w*hv.w;
    }
    // per-gate nonlinearity applied by the owning wave (wave-uniform branch)
    if (g == 2) r = tanhf(r);
    else if (g == 3) r = 1.f/(1.f+expf(-r));
    rec[g][e] = r;
    __syncthreads();
    if (tid < 64) {
      const float it = rec[0][e], ft = rec[1][e];
      const float zt = rec[2][e];
      const float ot = rec[3][e];
      const float mn = fmaxf(ft + m, it);
      const float ig = expf(it - mn);
      const float fg = expf(ft + m - mn);
      c = fg*c + ig*zt;
      n = fg*n + ig;
      m = mn;
      const float hn = ot*c/fmaxf(n, 1e-6f);
      hlds[e] = hn;
      hs[(long)(b*T_+t)*D_ + hd*64 + e] = hn;
    }
    __syncthreads();
  }
}

// ---------------- sLSTM scan (fallback, reads raw Rg) ----------------
__global__ __launch_bounds__(256) void slstm_scan(
    const float* __restrict__ g4, const void* __restrict__ Rg, long offR,
    float* __restrict__ hs, const int* __restrict__ dflag)
{
  const int isbf = *dflag;
  const int blk = blockIdx.x;
  const int b = blk >> 3, hd = blk & 7;
  const int tid = threadIdx.x;
  const int g = tid >> 6, e = tid & 63;
  float w[64];
  {
    const long wp = offR + ((long)(g*NH_ + hd)*64)*64 + e;
#pragma unroll
    for (int d = 0; d < 64; d++) w[d] = ldin(Rg, wp + d*64, isbf);
  }
  __shared__ float hlds[64];
  __shared__ float rec[4][64];
  if (tid < 64) hlds[tid] = 0.f;
  float c = 0.f, n = 0.f, m = 0.f;
  __syncthreads();
  const long gate_base = (long)(b*T_)*D_ + hd*64 + e;
  for (int t = 0; t < T_; t++) {
    float r = 0.f;
#pragma unroll
    for (int d4 = 0; d4 < 16; d4++) {
      const float4 hv = *(const float4*)(&hlds[d4*4]);
      r += w[4*d4]*hv.x + w[4*d4+1]*hv.y + w[4*d4+2]*hv.z + w[4*d4+3]*hv.w;
    }
    r += g4[(long)g*BT_*D_ + gate_base + (long)t*D_];
    rec[g][e] = r;
    __syncthreads();
    if (tid < 64) {
      const float it = rec[0][e], ft = rec[1][e];
      const float zt = tanhf(rec[2][e]);
      const float ot = 1.f/(1.f+expf(-rec[3][e]));
      const float mn = fmaxf(ft + m, it);
      const float ig = expf(it - mn);
      const float fg = expf(ft + m - mn);
      c = fg*c + ig*zt;
      n = fg*n + ig;
      m = mn;
      const float hn = ot*c/fmaxf(n, 1e-6f);
      hlds[e] = hn;
      hs[(long)(b*T_+t)*D_ + hd*64 + e] = hn;
    }
    __syncthreads();
  }
}

// ---------------- head_norm(dh=64) * gn, accumulated into h ----------------
__global__ __launch_bounds__(64) void hn_add(
    const float* __restrict__ hs, const void* __restrict__ gn, long offG,
    float* __restrict__ h, const int* __restrict__ dflag)
{
  const int isbf = *dflag;
  const int blk = blockIdx.x;
  const int bt = blk >> 3, hd = blk & 7;
  const int e = threadIdx.x;
  const long idx = (long)bt*D_ + hd*64 + e;
  const float x = hs[idx];
  float s1 = x, s2 = x*x;
#pragma unroll
  for (int o = 32; o > 0; o >>= 1) { s1 += __shfl_xor(s1, o); s2 += __shfl_xor(s2, o); }
  const float mu = s1*(1.f/64.f);
  const float var = s2*(1.f/64.f) - mu*mu;
  const float y = (x-mu)*rsqrtf(var+EPS_)*ldin(gn, offG + hd*64+e, isbf);
  h[idx] += y;
}

// ---------------- FF gating: gelu(g)*up, written with 704 stride (zero pad) ----------------
__global__ void ffgate(const float* __restrict__ u, float* __restrict__ out)
{
  const long total = (long)BT_*FFP_;
  for (long idx = (long)blockIdx.x*256 + threadIdx.x; idx < total;
       idx += (long)gridDim.x*256) {
    const long m = idx / FFP_;
    const int j = (int)(idx % FFP_);
    float r = 0.f;
    if (j < FF_) {
      const float g = u[m*FF2_ + j];
      r = geluf(g) * u[m*FF2_ + FF_ + j];
    }
    out[idx] = r;
  }
}

// ---------------- mLSTM gate cumsum: one block per (b, head) ----------------
__global__ __launch_bounds__(256) void mlstm_cf(
    const float* __restrict__ g16, float* __restrict__ cf, float* __restrict__ logi)
{
  const int bh = blockIdx.x;
  const int b = bh >> 3, hd = bh & 7;
  const int tid = threadIdx.x;
  __shared__ float slf[T_];
  if (tid < T_) {
    const float gf = g16[(long)(b*T_+tid)*16 + 8 + hd];
    const float ls = (gf >= 0.f) ? -log1pf(expf(-gf)) : (gf - log1pf(expf(gf)));
    slf[tid] = ls;
    logi[(long)bh*T_ + tid] = g16[(long)(b*T_+tid)*16 + hd];
  }
  __syncthreads();
  if (tid == 0) {
    float a = 0.f;
    for (int t = 0; t < T_; t++) { a += slf[t]; slf[t] = a; }
  }
  __syncthreads();
  if (tid < T_) cf[(long)bh*T_ + tid] = slf[tid];
}

// ---------------- MFMA flash attention ----------------
#define QPD 136
#define VPD 72
__global__ __launch_bounds__(256) void attn_mfma(
    const float* __restrict__ q, const unsigned short* __restrict__ k,
    const unsigned short* __restrict__ v, const float* __restrict__ cf,
    const float* __restrict__ li, float* __restrict__ hatt)
{
  const int tt = blockIdx.x, bh = blockIdx.y;
  const int b = bh >> 3, hd = bh & 7;
  const int t0 = tt*64;
  const int tid = threadIdx.x;
  const int w = tid >> 6, lane = tid & 63;
  const int lr = lane & 15, lq = lane >> 4;

  __shared__ unsigned short sQ[64*QPD];
  __shared__ unsigned short sK[64*QPD];
  __shared__ unsigned short sVt[128*VPD];
  __shared__ unsigned short sS[64*VPD];
  __shared__ float scft[64], scfs[64], slis[64];

  for (int idx = tid; idx < 64*64; idx += 256){
    int r = idx >> 6, dp = idx & 63;
    int t = t0 + r;
    unsigned pk = 0;
    if (t < T_){
      const float* qp = q + ((long)(b*T_+t))*DI_ + hd*DHI_ + dp*2;
      pk = packbf(qp[0], qp[1]);
    }
    *(unsigned*)&sQ[r*QPD + dp*2] = pk;
  }
  if (tid < 64) scft[tid] = (t0+tid < T_) ? cf[(long)bh*T_ + t0+tid] : 0.f;

  float m_st[4], s_st[4], alpha_[4];
#pragma unroll
  for (int rr=0;rr<4;rr++){ m_st[rr] = -INFINITY; s_st[rr] = 0.f; }
  floatx4 accO[8];
#pragma unroll
  for (int nd=0;nd<8;nd++)
#pragma unroll
    for (int rr=0;rr<4;rr++) accO[nd][rr] = 0.f;

  for (int st = 0; st <= tt; st++){
    const int s0 = st*64;
    for (int idx = tid; idx < 64*64; idx += 256){
      int r = idx >> 6, dp = idx & 63;
      int s = s0 + r;
      unsigned pkk = 0, pkv = 0;
      if (s < T_){
        const long base = ((long)(b*T_+s))*DI_ + hd*DHI_ + dp*2;
        pkk = *(const unsigned*)&k[base];
        pkv = *(const unsigned*)&v[base];
      }
      *(unsigned*)&sK[r*QPD + dp*2] = pkk;
      sVt[(dp*2)*VPD + r]   = (unsigned short)(pkv & 0xFFFFu);
      sVt[(dp*2+1)*VPD + r] = (unsigned short)(pkv >> 16);
    }
    if (tid < 64){
      int s = s0 + tid;
      scfs[tid] = (s < T_) ? cf[(long)bh*T_ + s] : 0.f;
      slis[tid] = (s < T_) ? li[(long)bh*T_ + s] : 0.f;
    }
    __syncthreads();

    floatx4 accS[4];
#pragma unroll
    for (int ni=0;ni<4;ni++)
#pragma unroll
      for (int rr=0;rr<4;rr++) accS[ni][rr] = 0.f;
    const int qrow = w*16 + lr;
#pragma unroll
    for (int k0=0;k0<4;k0++){
      short8 a = *(const short8*)&sQ[qrow*QPD + k0*32 + lq*8];
#pragma unroll
      for (int ni=0;ni<4;ni++){
        short8 bb = *(const short8*)&sK[(ni*16+lr)*QPD + k0*32 + lq*8];
        accS[ni] = __builtin_amdgcn_mfma_f32_16x16x32_bf16(a, bb, accS[ni], 0,0,0);
      }
    }

#pragma unroll
    for (int rr=0;rr<4;rr++){
      const int tg = t0 + w*16 + lq*4 + rr;
      const float cftr = scft[w*16 + lq*4 + rr];
      float dmv[4];
      float mx = -INFINITY;
#pragma unroll
      for (int ni=0;ni<4;ni++){
        const int sg = s0 + ni*16 + lr;
        const bool valid = (tg < T_) && (sg <= tg);
        dmv[ni] = valid ? (cftr - scfs[ni*16+lr] + slis[ni*16+lr]) : -INFINITY;
        mx = fmaxf(mx, dmv[ni]);
      }
      mx = fmaxf(mx, __shfl_xor(mx, 1));
      mx = fmaxf(mx, __shfl_xor(mx, 2));
      mx = fmaxf(mx, __shfl_xor(mx, 4));
      mx = fmaxf(mx, __shfl_xor(mx, 8));
      const float mnew = fmaxf(m_st[rr], mx);
      const float al = (mnew == -INFINITY) ? 0.f : expf(m_st[rr] - mnew);
      float rs = 0.f;
#pragma unroll
      for (int ni=0;ni<4;ni++){
        const float wexp = (dmv[ni] == -INFINITY) ? 0.f : expf(dmv[ni] - mnew);
        const float pv = accS[ni][rr]*wexp;
        rs += pv;
        sS[(w*16 + lq*4 + rr)*VPD + ni*16 + lr] = f2bu(pv);
      }
      rs += __shfl_xor(rs, 1);
      rs += __shfl_xor(rs, 2);
      rs += __shfl_xor(rs, 4);
      rs += __shfl_xor(rs, 8);
      s_st[rr] = s_st[rr]*al + rs;
      m_st[rr] = mnew;
      alpha_[rr] = al;
    }

#pragma unroll
    for (int nd=0;nd<8;nd++)
#pragma unroll
      for (int rr=0;rr<4;rr++) accO[nd][rr] *= alpha_[rr];

#pragma unroll
    for (int ks=0;ks<2;ks++){
      short8 aP = *(const short8*)&sS[(w*16 + lr)*VPD + ks*32 + lq*8];
#pragma unroll
      for (int nd=0;nd<8;nd++){
        short8 bV = *(const short8*)&sVt[(nd*16+lr)*VPD + ks*32 + lq*8];
        accO[nd] = __builtin_amdgcn_mfma_f32_16x16x32_bf16(aP, bV, accO[nd], 0,0,0);
      }
    }
    __syncthreads();
  }

#pragma unroll
  for (int rr=0;rr<4;rr++){
    const int tg = t0 + w*16 + lq*4 + rr;
    if (tg >= T_) continue;
    const float inv = 1.f / fmaxf(fabsf(s_st[rr]), expf(-m_st[rr]));
    float* op = hatt + ((long)(b*T_+tg))*DI_ + hd*DHI_;
#pragma unroll
    for (int nd=0;nd<8;nd++)
      op[nd*16 + lr] = accO[nd][rr]*inv;
  }
}

// ---------------- head_norm(dh=128)*gn + skip*xc, then *silu(z) ----------------
__global__ __launch_bounds__(128) void hn_mlstm(
    const float* __restrict__ hatt, const void* __restrict__ gn, long offG,
    const void* __restrict__ skip, long offSk, const float* __restrict__ xc,
    const float* __restrict__ u, float* __restrict__ gin,
    const int* __restrict__ dflag)
{
  const int isbf = *dflag;
  const int blk = blockIdx.x;
  const int bt = blk >> 3, hd = blk & 7;
  const int e = threadIdx.x;
  const int j = hd*DHI_ + e;
  const long idx = (long)bt*DI_ + j;
  const float x = hatt[idx];
  __shared__ float r1[128], r2[128];
  r1[e]=x; r2[e]=x*x; __syncthreads();
  for (int o=64;o>0;o>>=1){ if(e<o){r1[e]+=r1[e+o]; r2[e]+=r2[e+o];} __syncthreads(); }
  const float mu = r1[0]*(1.f/128.f);
  const float var = r2[0]*(1.f/128.f)-mu*mu;
  const float y = (x-mu)*rsqrtf(var+EPS_)*ldin(gn, offG+j, isbf) + ldin(skip, offSk+j, isbf)*xc[idx];
  const float z = u[(long)bt*2048 + DI_ + j];
  gin[idx] = y * siluf(z);
}

// ---------------- final transpose to output ----------------
__global__ void out_transpose(const float* __restrict__ hp, void* __restrict__ out,
                              const int* __restrict__ dflag)
{
  const int isbf = *dflag;
  const int tid = threadIdx.x;
  if (tid < B_*6) {
    const int b = tid / 6, hd = tid % 6;
    const float v = hp[hd*B_ + b];
    if (isbf) ((bf16*)out)[tid] = __float2bfloat16(v);
    else      ((float*)out)[tid] = v;
  }
}

extern "C" void kernel_launch(void* const* d_in, const int* in_sizes, int n_in,
                              void* d_out, int out_size, void* d_ws, size_t ws_size,
                              hipStream_t stream)
{
  (void)in_sizes; (void)n_in; (void)out_size;
  const void* x        = d_in[0];
  const void* w_in     = d_in[1];
  const void* b_in     = d_in[2];
  const void* ln_in_s  = d_in[3];
  const void* ln_in_b  = d_in[4];
  const void* s_ln_s   = d_in[5];
  const void* s_ln_b   = d_in[6];
  const void* s_conv_w = d_in[7];
  const void* s_conv_b = d_in[8];
  const void* s_wg     = d_in[9];
  const void* s_rg     = d_in[10];
  const void* s_bg     = d_in[11];
  const void* s_gn     = d_in[12];
  const void* s_ffln_s = d_in[13];
  const void* s_ffln_b = d_in[14];
  const void* s_ff_w1  = d_in[15];
  const void* s_ff_w2  = d_in[16];
  const void* m_ln_s   = d_in[17];
  const void* m_ln_b   = d_in[18];
  const void* m_w_up   = d_in[19];
  const void* m_conv_w = d_in[20];
  const void* m_conv_b = d_in[21];
  const void* m_wq     = d_in[22];
  const void* m_wk     = d_in[23];
  const void* m_wv     = d_in[24];
  const void* m_w_if   = d_in[25];
  const void* m_b_if   = d_in[26];
  const void* m_skip   = d_in[27];
  const void* m_gn     = d_in[28];
  const void* m_w_down = d_in[29];
  const void* post_ln_s= d_in[30];
  const void* post_ln_b= d_in[31];
  const void* hw1      = d_in[32];
  const void* hb1      = d_in[33];
  const void* hw2      = d_in[34];
  const void* hb2      = d_in[35];
  const void* hw3      = d_in[36];
  const void* hb3      = d_in[37];

  float* W   = (float*)d_ws;
  float* h   = W;                           // BT*D
  float* xn  = W + 4128768L;                // BT*D
  float* xc  = W + 8257536L;                // BT*DI
  float* u   = W + 16515072L;               // 4*BT*D
  float* q   = W + 33030144L;               // BT*DI fp32 (hs / ffg(704) / hatt / gin)
  unsigned short* kk_ = (unsigned short*)(W + 41287680L); // BT*DI bf16
  unsigned short* vv_ = (unsigned short*)(W + 45416448L); // BT*DI bf16
  float* g16 = W + 49545216L;               // BT*16
  float* cfb = W + 49674240L;               // B*NH*T
  float* lib = W + 49738752L;               // B*NH*T
  float* last= W + 49803264L;               // 32*512
  float* ha1 = W + 49819648L;               // 6*32*256
  float* ha2 = W + 49868800L;               // 6*32*128
  float* hp  = W + 49893376L;               // 6*32 (pad)
  int*   dfl = (int*)(W + 49893568L);
  float* wsRg = W + 49893632L;              // 4 layers x 4x8x64x64 fp32 = 524288 floats

  // bf16 weight planes (hi, lo), each PLANE ushorts, k-contiguous [N][K]
  const long PLANE = 14327808L;
  unsigned short* wtHi = (unsigned short*)(W + 50417920L);
  unsigned short* wtLo = wtHi + PLANE;
  const long oWg=0, oF1=4194304L, oF2=6987776L, oUp=8429568L;
  const long oQ=11575296L, oK=11968512L, oV=12361728L, oDn=12754944L;

  const size_t needFull = (size_t)(50417920L + PLANE)*4;            // ~259.0 MB
  const size_t needMid  = (size_t)(50417920L + PLANE/2)*4 + PLANE;  // tier1: hi plane only
  const int tier = (ws_size >= needFull) ? 2 : ((ws_size >= needMid) ? 1 : 0);
  const int spB = (tier == 2) ? 1 : 0;
  unsigned short* loArg = (tier == 2) ? wtLo : nullptr;

  const float kscale = 0.08838834764831845f; // 1/sqrt(128)

  detect_dtype<<<1, 64, 0, stream>>>((const unsigned*)ln_in_s, dfl);

  if (tier >= 1) {
    rg_prep<<<128, 256, 0, stream>>>(s_rg, wsRg, dfl);
    wt_transpose2<<<dim3(16,16,16),256,0,stream>>>(s_wg, 0, 262144L, 512, 512, 512,
        wtHi+oWg, loArg?loArg+oWg:nullptr, 262144L, dfl);
    wt_transpose2<<<dim3(43,16,4),256,0,stream>>>(s_ff_w1, 0, 698368L, 512, 1364, 512,
        wtHi+oF1, loArg?loArg+oF1:nullptr, 698368L, dfl);
    wt_transpose2<<<dim3(16,22,4),256,0,stream>>>(s_ff_w2, 0, 349184L, 682, 512, 704,
        wtHi+oF2, loArg?loArg+oF2:nullptr, 360448L, dfl);
    wt_transpose2<<<dim3(64,16,3),256,0,stream>>>(m_w_up, 0, 1048576L, 512, 2048, 512,
        wtHi+oUp, loArg?loArg+oUp:nullptr, 1048576L, dfl);
    wt_transpose2<<<dim3(4,4,24),256,0,stream>>>(m_wq, 0, 16384L, 128, 128, 128,
        wtHi+oQ, loArg?loArg+oQ:nullptr, 16384L, dfl);
    wt_transpose2<<<dim3(4,4,24),256,0,stream>>>(m_wk, 0, 16384L, 128, 128, 128,
        wtHi+oK, loArg?loArg+oK:nullptr, 16384L, dfl);
    wt_transpose2<<<dim3(4,4,24),256,0,stream>>>(m_wv, 0, 16384L, 128, 128, 128,
        wtHi+oV, loArg?loArg+oV:nullptr, 16384L, dfl);
    wt_transpose2<<<dim3(16,32,3),256,0,stream>>>(m_w_down, 0, 524288L, 1024, 512, 1024,
        wtHi+oDn, loArg?loArg+oDn:nullptr, 524288L, dfl);
  }

  ln_proj<<<BT_, 256, 0, stream>>>(x, w_in, b_in, ln_in_s, ln_in_b, h, dfl);

  int si = 0, mi = 0;
  for (int blk = 0; blk < 7; blk++) {
    if ((blk & 1) == 0) {
      // ---- sLSTM block ----
      ln_rows<<<BT_,256,0,stream>>>(h, 512L, s_ln_s, (long)si*512, s_ln_b, (long)si*512, xn, dfl);
      {
        long tot = (long)BT_*512; int g = (int)((tot+255)/256);
        conv_silu<<<g,256,0,stream>>>(xn, 512, s_conv_w, (long)si*4*512, s_conv_b, (long)si*512, xc, 512, dfl);
      }
      if (tier >= 1) {
        gemm_split<<<dim3(8,126,4),256,0,stream>>>(xc, xn, 2, 0L,
            wtHi+oWg+(long)si*4*262144L, wtLo+oWg+(long)si*4*262144L,
            s_bg, (long)si*4*512, u,
            512, 512, 512, 512, 262144L, (long)BT_*512, 512L, 1.f, 1, spB, dfl);
      } else {
        for (int g = 0; g < 4; g++) {
          const float* Ain = (g < 2) ? xc : xn;
          gemm_f32b<<<dim3(8,126,1),256,0,stream>>>(Ain, s_wg, ((long)(si*4+g))*512*512,
              s_bg, (long)(si*4+g)*512, u + (long)g*BT_*512,
              BT_, 512, 512, 512, 512, 512, 0,0,0,0, 1.f, 1, dfl);
        }
      }
      if (tier >= 1)
        slstm_scan3<<<256,256,0,stream>>>(u, wsRg + (long)si*131072L, q /*hs*/);
      else
        slstm_scan<<<256,256,0,stream>>>(u, s_rg, (long)si*4*8*64*64, q /*hs*/, dfl);
      hn_add<<<BT_*8,64,0,stream>>>(q, s_gn, (long)si*512, h, dfl);
      // ---- FF block ----
      ln_rows<<<BT_,256,0,stream>>>(h, 512L, s_ffln_s, (long)si*512, s_ffln_b, (long)si*512, xn, dfl);
      if (tier >= 1)
        gemm_split<<<dim3(22,126,1),256,0,stream>>>(xn, xn, 9, 0L,
            wtHi+oF1+(long)si*698368L, wtLo+oF1+(long)si*698368L, nullptr, 0,
            u, 1364, 512, 512, 1364, 0,0,0, 1.f, 0, spB, dfl);
      else
        gemm_f32b<<<dim3(22,126,1),256,0,stream>>>(xn, s_ff_w1, (long)si*512*1364, nullptr, 0,
            u, BT_, 1364, 512, 512, 1364, 1364, 0,0,0,0, 1.f, 0, dfl);
      {
        long tot = (long)BT_*FFP_; int g = (int)((tot+255)/256);
        ffgate<<<g,256,0,stream>>>(u, q /*ffg, stride 704*/);
      }
      if (tier >= 1)
        gemm_split<<<dim3(8,126,1),256,0,stream>>>(q, q, 9, 0L,
            wtHi+oF2+(long)si*360448L, wtLo+oF2+(long)si*360448L, nullptr, 0,
            h, 512, 704, 704, 512, 0,0,0, 1.f, 2, spB, dfl);
      else
        gemm_f32b<<<dim3(8,126,1),256,0,stream>>>(q, s_ff_w2, (long)si*682*512, nullptr, 0,
            h, BT_, 512, 682, 704, 512, 512, 0,0,0,0, 1.f, 2, dfl);
      si++;
    } else {
      // ---- mLSTM block ----
      ln_rows<<<BT_,256,0,stream>>>(h, 512L, m_ln_s, (long)mi*512, m_ln_b, (long)mi*512, xn, dfl);
      if (tier >= 1)
        gemm_split<<<dim3(32,126,1),256,0,stream>>>(xn, xn, 9, 0L,
            wtHi+oUp+(long)mi*1048576L, wtLo+oUp+(long)mi*1048576L, nullptr, 0,
            u, 2048, 512, 512, 2048, 0,0,0, 1.f, 0, spB, dfl);
      else
        gemm_f32b<<<dim3(32,126,1),256,0,stream>>>(xn, m_w_up, (long)mi*512*2048, nullptr, 0,
            u, BT_, 2048, 512, 512, 2048, 2048, 0,0,0,0, 1.f, 0, dfl);
      {
        long tot = (long)BT_*1024; int g = (int)((tot+255)/256);
        conv_silu<<<g,256,0,stream>>>(u, 2048, m_conv_w, (long)mi*4*1024, m_conv_b, (long)mi*1024, xc, 1024, dfl);
      }
      if (tier >= 1) {
        gemm_split<<<dim3(2,126,8),256,0,stream>>>(xc, xc, 9, 128L,
            wtHi+oQ+(long)mi*131072L, wtLo+oQ+(long)mi*131072L, nullptr, 0,
            q, 128, 128, 1024, 1024, 16384L, 128L, 0, 1.f, 0, spB, dfl);
        gemm_split<<<dim3(2,126,8),256,0,stream>>>(xc, xc, 9, 128L,
            wtHi+oK+(long)mi*131072L, wtLo+oK+(long)mi*131072L, nullptr, 0,
            (float*)kk_, 128, 128, 1024, 1024, 16384L, 128L, 0, kscale, 8, spB, dfl);
        gemm_split<<<dim3(2,126,8),256,0,stream>>>(u, u, 9, 128L,
            wtHi+oV+(long)mi*131072L, wtLo+oV+(long)mi*131072L, nullptr, 0,
            (float*)vv_, 128, 128, 2048, 1024, 16384L, 128L, 0, 1.f, 8, spB, dfl);
      } else {
        gemm_f32b<<<dim3(2,126,8),256,0,stream>>>(xc, m_wq, (long)mi*8*128*128, nullptr, 0,
            q, BT_, 128, 128, 1024, 128, 1024, 128, 16384, 128, 0, 1.f, 0, dfl);
        gemm_f32b<<<dim3(2,126,8),256,0,stream>>>(xc, m_wk, (long)mi*8*128*128, nullptr, 0,
            (float*)kk_, BT_, 128, 128, 1024, 128, 1024, 128, 16384, 128, 0, kscale, 8, dfl);
        gemm_f32b<<<dim3(2,126,8),256,0,stream>>>(u, m_wv, (long)mi*8*128*128, nullptr, 0,
            (float*)vv_, BT_, 128, 128, 2048, 128, 1024, 128, 16384, 128, 0, 1.f, 8, dfl);
      }
      gemm_f32b<<<dim3(1,126,1),256,0,stream>>>(xc, m_w_if, (long)mi*1024*16, m_b_if, (long)mi*16,
            g16, BT_, 16, 1024, 1024, 16, 16, 0,0,0,0, 1.f, 1, dfl);
      mlstm_cf<<<256,256,0,stream>>>(g16, cfb, lib);
      attn_mfma<<<dim3(4,256),256,0,stream>>>(q, kk_, vv_, cfb, lib, q /*hatt in-place*/);
      hn_mlstm<<<BT_*8,128,0,stream>>>(q, m_gn, (long)mi*1024, m_skip, (long)mi*1024, xc, u, q, dfl);
      if (tier >= 1)
        gemm_split<<<dim3(8,126,1),256,0,stream>>>(q, q, 9, 0L,
            wtHi+oDn+(long)mi*524288L, wtLo+oDn+(long)mi*524288L, nullptr, 0,
            h, 512, 1024, 1024, 512, 0,0,0, 1.f, 2, spB, dfl);
      else
        gemm_f32b<<<dim3(8,126,1),256,0,stream>>>(q, m_w_down, (long)mi*1024*512, nullptr, 0,
            h, BT_, 512, 1024, 1024, 512, 512, 0,0,0,0, 1.f, 2, dfl);
      mi++;
    }
  }

  // post-LN on last timestep rows only
  ln_rows<<<B_,256,0,stream>>>(h + (long)(T_-1)*512, (long)T_*512, post_ln_s, 0, post_ln_b, 0, last, dfl);

  // 6 prediction heads, batched over grid.z (tiny; SIMT fp32)
  gemm_f32b<<<dim3(4,1,6),256,0,stream>>>(last, hw1, 0, hb1, 0, ha1, 32, 256, 512, 512, 256, 256,
        0, 512L*256, 32L*256, 256, 1.f, 1|4, dfl);
  gemm_f32b<<<dim3(2,1,6),256,0,stream>>>(ha1, hw2, 0, hb2, 0, ha2, 32, 128, 256, 256, 128, 128,
        32L*256, 256L*128, 32L*128, 128, 1.f, 1|4, dfl);
  gemm_f32b<<<dim3(1,1,6),256,0,stream>>>(ha2, hw3, 0, hb3, 0, hp, 32, 1, 128, 128, 1, 1,
        32L*128, 128L, 32L, 1, 1.f, 1, dfl);
  out_transpose<<<1,256,0,stream>>>(hp, d_out, dfl);
}

// Round 9
// 3922.226 us; speedup vs baseline: 1.0863x; 1.0343x over previous
//
#include <hip/hip_runtime.h>
#include <hip/hip_bf16.h>
#include <cmath>

typedef __hip_bfloat16 bf16;

#define B_   32
#define T_   252
#define F_   8
#define D_   512
#define NH_  8
#define DH_  64
#define DI_  1024
#define DHI_ 128
#define FF_  682
#define FF2_ 1364
#define FFP_ 704
#define BT_  (B_*T_)
#define EPS_ 1e-5f

typedef __attribute__((ext_vector_type(8))) short short8;
typedef __attribute__((ext_vector_type(4))) float floatx4;

__device__ __forceinline__ float b2f(bf16 v){ return __bfloat162float(v); }
__device__ __forceinline__ float siluf(float x){ return x/(1.f+expf(-x)); }
__device__ __forceinline__ float geluf(float x){
  float x3 = x*x*x;
  return 0.5f*x*(1.f+tanhf(0.7978845608028654f*(x+0.044715f*x3)));
}
__device__ __forceinline__ float ldin(const void* p, long i, int isbf){
  return isbf ? __bfloat162float(((const bf16*)p)[i]) : ((const float*)p)[i];
}
__device__ __forceinline__ unsigned short f2bu(float f){
  bf16 h = __float2bfloat16(f);
  return *(reinterpret_cast<unsigned short*>(&h));
}
__device__ __forceinline__ void split2(float v, unsigned short& h, unsigned short& l){
  bf16 hb = __float2bfloat16(v);
  h = *(reinterpret_cast<unsigned short*>(&hb));
  float r = v - __bfloat162float(hb);
  bf16 lb = __float2bfloat16(r);
  l = *(reinterpret_cast<unsigned short*>(&lb));
}
__device__ __forceinline__ unsigned packbf(float x, float y){
  return (unsigned)f2bu(x) | ((unsigned)f2bu(y) << 16);
}

__global__ void detect_dtype(const unsigned* __restrict__ probe, int* __restrict__ flag)
{
  if (threadIdx.x == 0) *flag = (*probe == 0x3F803F80u) ? 1 : 0;
}

// ---- sLSTM recurrent weight prep: Rg [si][g][hd][d][e] -> fp32 [(si*4+g)*8+hd][e][d] ----
__global__ __launch_bounds__(256) void rg_prep(
    const void* __restrict__ Rg, float* __restrict__ out, const int* __restrict__ dflag)
{
  const int isbf = *dflag;
  const int c = blockIdx.x;          // 0..127 = (si*4+g)*8+hd
  const long base = (long)c*4096;
  __shared__ float tl[64][65];
  const int col = threadIdx.x & 63, r4 = threadIdx.x >> 6;
#pragma unroll
  for (int i=0;i<16;i++){
    int d = i*4 + r4;
    tl[d][col] = ldin(Rg, base + (long)d*64 + col, isbf);
  }
  __syncthreads();
#pragma unroll
  for (int i=0;i<16;i++){
    int e = i*4 + r4;
    out[base + (long)e*64 + col] = tl[col][e];
  }
}

// ---- weight transpose + hi/lo bf16 split: in [K][N] -> planes [N][outK] (outK>=K zero-pad) ----
__global__ __launch_bounds__(256) void wt_transpose2(
    const void* __restrict__ in, long inOff, long inStride, int K, int N, int outK,
    unsigned short* __restrict__ outHi, unsigned short* __restrict__ outLo,
    long outStride, const int* __restrict__ dflag)
{
  const int isbf = *dflag;
  const int bz = blockIdx.z;
  const long base = inOff + (long)bz*inStride;
  unsigned short* oh = outHi + (long)bz*outStride;
  unsigned short* ol = outLo ? outLo + (long)bz*outStride : nullptr;
  __shared__ float tile[32][33];
  const int k0 = blockIdx.y*32, n0 = blockIdx.x*32;
  const int tn = threadIdx.x & 31, tk = threadIdx.x >> 5;
#pragma unroll
  for (int i=0;i<4;i++){
    int kk = tk + i*8;
    float v = 0.f;
    if (k0+kk < K && n0+tn < N) v = ldin(in, base + (long)(k0+kk)*N + n0+tn, isbf);
    tile[kk][tn] = v;
  }
  __syncthreads();
#pragma unroll
  for (int i=0;i<4;i++){
    int nn = tk + i*8;
    if (n0+nn < N && k0+tn < outK){
      unsigned short h, l;
      split2(tile[tn][nn], h, l);
      oh[(long)(n0+nn)*outK + k0+tn] = h;
      if (ol) ol[(long)(n0+nn)*outK + k0+tn] = l;
    }
  }
}

// ---- split-bf16 MFMA GEMM: C = alpha*(A@B) [+bias] [+C] ----
// flags: 1=bias, 2=accumulate, 8=store C as packed bf16 (ushort)
__global__ __launch_bounds__(256) void gemm_split(
    const float* __restrict__ A0, const float* __restrict__ A1, int zSplit, long strideA,
    const unsigned short* __restrict__ Bhi, const unsigned short* __restrict__ Blo,
    const void* __restrict__ bias, long offBias, float* __restrict__ C,
    int N, int K, int lda, int ldc,
    long strideBT, long strideC, long strideBias,
    float alpha, int flags, int splitB, const int* __restrict__ dflag)
{
  const int isbf = *dflag;
  const int bz = blockIdx.z;
  const float* A = ((bz < zSplit) ? A0 : A1) + (long)bz*strideA;
  const unsigned short* bhp = Bhi + (long)bz*strideBT;
  const unsigned short* blp = Blo + (long)bz*strideBT;
  const long cBase = (long)bz*strideC;
  const long bBias = offBias + (long)bz*strideBias;

  __shared__ unsigned short aH[64*72], aL[64*72], bH[64*72], bL[64*72];
  const int tid = threadIdx.x;
  const int wid = tid >> 6, lane = tid & 63;
  const int wm = (wid >> 1)*32, wn = (wid & 1)*32;
  const int m0 = blockIdx.y*64, n0 = blockIdx.x*64;
  const int lr = lane & 15, lq = lane >> 4;

  floatx4 acc[2][2];
#pragma unroll
  for (int mi=0;mi<2;mi++)
#pragma unroll
    for (int ni=0;ni<2;ni++)
#pragma unroll
      for (int r=0;r<4;r++) acc[mi][ni][r] = 0.f;

  const int sRow = tid >> 2;
  const int sSeg = (tid & 3)*16;

  for (int k0 = 0; k0 < K; k0 += 64) {
    {
      const float* ap = A + (long)(m0 + sRow)*lda + k0 + sSeg;
#pragma unroll
      for (int c=0;c<4;c++){
        const float4 v = *(const float4*)(ap + c*4);
        unsigned short h0,h1,h2,h3,l0,l1,l2,l3;
        split2(v.x,h0,l0); split2(v.y,h1,l1); split2(v.z,h2,l2); split2(v.w,h3,l3);
        uint2 ph, pl;
        ph.x = (unsigned)h0 | ((unsigned)h1<<16); ph.y = (unsigned)h2 | ((unsigned)h3<<16);
        pl.x = (unsigned)l0 | ((unsigned)l1<<16); pl.y = (unsigned)l2 | ((unsigned)l3<<16);
        *(uint2*)&aH[sRow*72 + sSeg + c*4] = ph;
        *(uint2*)&aL[sRow*72 + sSeg + c*4] = pl;
      }
    }
    {
      const int gn = n0 + sRow;
      const bool nv = gn < N;
      const long bo = (long)gn*K + k0 + sSeg;
      uint4 z4; z4.x=z4.y=z4.z=z4.w=0;
      uint4 h0 = nv ? *(const uint4*)(bhp + bo)     : z4;
      uint4 h1 = nv ? *(const uint4*)(bhp + bo + 8) : z4;
      *(uint4*)&bH[sRow*72 + sSeg]     = h0;
      *(uint4*)&bH[sRow*72 + sSeg + 8] = h1;
      if (splitB){
        uint4 l0_ = nv ? *(const uint4*)(blp + bo)     : z4;
        uint4 l1_ = nv ? *(const uint4*)(blp + bo + 8) : z4;
        *(uint4*)&bL[sRow*72 + sSeg]     = l0_;
        *(uint4*)&bL[sRow*72 + sSeg + 8] = l1_;
      }
    }
    __syncthreads();

#pragma unroll
    for (int ks=0;ks<2;ks++){
      short8 ah[2], al[2], bh_[2], bl_[2];
#pragma unroll
      for (int mi=0;mi<2;mi++){
        ah[mi] = *(const short8*)&aH[(wm+mi*16+lr)*72 + ks*32 + lq*8];
        al[mi] = *(const short8*)&aL[(wm+mi*16+lr)*72 + ks*32 + lq*8];
      }
#pragma unroll
      for (int ni=0;ni<2;ni++){
        bh_[ni] = *(const short8*)&bH[(wn+ni*16+lr)*72 + ks*32 + lq*8];
        if (splitB) bl_[ni] = *(const short8*)&bL[(wn+ni*16+lr)*72 + ks*32 + lq*8];
      }
#pragma unroll
      for (int mi=0;mi<2;mi++)
#pragma unroll
        for (int ni=0;ni<2;ni++){
          acc[mi][ni] = __builtin_amdgcn_mfma_f32_16x16x32_bf16(al[mi], bh_[ni], acc[mi][ni], 0,0,0);
          if (splitB)
            acc[mi][ni] = __builtin_amdgcn_mfma_f32_16x16x32_bf16(ah[mi], bl_[ni], acc[mi][ni], 0,0,0);
          acc[mi][ni] = __builtin_amdgcn_mfma_f32_16x16x32_bf16(ah[mi], bh_[ni], acc[mi][ni], 0,0,0);
        }
    }
    __syncthreads();
  }

#pragma unroll
  for (int mi=0;mi<2;mi++){
#pragma unroll
    for (int ni=0;ni<2;ni++){
      const int gn = n0 + wn + ni*16 + lr;
      if (gn >= N) continue;
      const float bv = (flags & 1) ? ldin(bias, bBias + gn, isbf) : 0.f;
#pragma unroll
      for (int rr=0;rr<4;rr++){
        const int gm = m0 + wm + mi*16 + lq*4 + rr;
        float vv = acc[mi][ni][rr]*alpha + bv;
        const long idx = cBase + (long)gm*ldc + gn;
        if (flags & 8) {
          ((unsigned short*)C)[idx] = f2bu(vv);
        } else {
          if (flags & 2) vv += C[idx];
          C[idx] = vv;
        }
      }
    }
  }
}

// ---------------- input projection + layernorm ----------------
__global__ __launch_bounds__(256) void ln_proj(
    const void* __restrict__ x, const void* __restrict__ w,
    const void* __restrict__ bb, const void* __restrict__ s,
    const void* __restrict__ b, float* __restrict__ out,
    const int* __restrict__ dflag)
{
  const int isbf = *dflag;
  const int r = blockIdx.x;
  const int tid = threadIdx.x;
  float xr[8];
#pragma unroll
  for (int f = 0; f < 8; f++) xr[f] = ldin(x, (long)r*8+f, isbf);
  float vv[2];
#pragma unroll
  for (int i2 = 0; i2 < 2; i2++) {
    const int j = tid + i2*256;
    float a = ldin(bb, j, isbf);
#pragma unroll
    for (int f = 0; f < 8; f++) a += xr[f]*ldin(w, f*512+j, isbf);
    vv[i2] = a;
  }
  __shared__ float r1[256], r2[256];
  r1[tid] = vv[0]+vv[1]; r2[tid] = vv[0]*vv[0]+vv[1]*vv[1];
  __syncthreads();
  for (int o = 128; o > 0; o >>= 1) {
    if (tid < o) { r1[tid]+=r1[tid+o]; r2[tid]+=r2[tid+o]; }
    __syncthreads();
  }
  const float mu = r1[0]*(1.f/512.f);
  const float var = r2[0]*(1.f/512.f)-mu*mu;
  const float rstd = rsqrtf(var+EPS_);
  float* orow = out + (long)r*512;
#pragma unroll
  for (int i2 = 0; i2 < 2; i2++) {
    const int j = tid + i2*256;
    orow[j] = (vv[i2]-mu)*rstd*ldin(s, j, isbf) + ldin(b, j, isbf);
  }
}

// ---------------- layernorm over 512-elem rows ----------------
__global__ __launch_bounds__(256) void ln_rows(
    const float* __restrict__ in, long rowStride,
    const void* __restrict__ s, long offS,
    const void* __restrict__ b, long offB,
    float* __restrict__ out, const int* __restrict__ dflag)
{
  const int isbf = *dflag;
  const long r = blockIdx.x;
  const int tid = threadIdx.x;
  const float* xr = in + r*rowStride;
  const float v0 = xr[tid], v1 = xr[tid+256];
  __shared__ float r1[256], r2[256];
  r1[tid] = v0+v1; r2[tid] = v0*v0+v1*v1;
  __syncthreads();
  for (int o = 128; o > 0; o >>= 1) {
    if (tid < o) { r1[tid]+=r1[tid+o]; r2[tid]+=r2[tid+o]; }
    __syncthreads();
  }
  const float mu = r1[0]*(1.f/512.f);
  const float var = r2[0]*(1.f/512.f)-mu*mu;
  const float rstd = rsqrtf(var+EPS_);
  float* orow = out + r*(long)D_;
  orow[tid]     = (v0-mu)*rstd*ldin(s, offS+tid, isbf)     + ldin(b, offB+tid, isbf);
  orow[tid+256] = (v1-mu)*rstd*ldin(s, offS+tid+256, isbf) + ldin(b, offB+tid+256, isbf);
}

// ---------------- causal conv(K=4) + silu ----------------
__global__ void conv_silu(const float* __restrict__ in, int inStride,
                          const void* __restrict__ w, long offW,
                          const void* __restrict__ bias, long offBias,
                          float* __restrict__ out, int Dc,
                          const int* __restrict__ dflag)
{
  const int isbf = *dflag;
  const long total = (long)BT_ * Dc;
  for (long idx = (long)blockIdx.x*256 + threadIdx.x; idx < total;
       idx += (long)gridDim.x*256) {
    const int d = (int)(idx % Dc);
    const long bt = idx / Dc;
    const int b = (int)(bt / T_), t = (int)(bt % T_);
    float a = ldin(bias, offBias + d, isbf);
#pragma unroll
    for (int kk = 0; kk < 4; kk++) {
      const int ts = t - 3 + kk;
      if (ts >= 0) a += ldin(w, offW + kk*Dc + d, isbf) * in[((long)(b*T_+ts))*inStride + d];
    }
    out[idx] = siluf(a);
  }
}

// ---------------- fallback SIMT GEMM ----------------
__global__ __launch_bounds__(256) void gemm_f32b(
    const float* __restrict__ A, const void* __restrict__ Bw, long offB,
    const void* __restrict__ bias, long offBias, float* __restrict__ C,
    int M, int N, int K, int lda, int ldb, int ldc,
    long strideA, long strideB, long strideC, long strideBias,
    float alpha, int flags, const int* __restrict__ dflag)
{
  const int isbf = *dflag;
  const int bz = blockIdx.z;
  A  += (long)bz * strideA;
  const long bB = offB + (long)bz * strideB;
  const long cBase = (long)bz * strideC;
  const long bBias = offBias + (long)bz * strideBias;
  __shared__ float sA[16][68];
  __shared__ float sB[16][64];
  const int tid = threadIdx.x;
  const int tx = tid & 15, ty = tid >> 4;
  const int m0 = blockIdx.y * 64, n0 = blockIdx.x * 64;
  float acc[4][4];
#pragma unroll
  for (int i=0;i<4;i++)
#pragma unroll
    for (int j=0;j<4;j++) acc[i][j]=0.f;

  for (int k0 = 0; k0 < K; k0 += 16) {
#pragma unroll
    for (int r = 0; r < 4; r++) {
      int lin = tid + r*256;
      int kk = lin & 15, m = lin >> 4;
      int gm = m0 + m, gk = k0 + kk;
      sA[kk][m] = (gm < M && gk < K) ? A[(long)gm*lda + gk] : 0.f;
    }
#pragma unroll
    for (int r = 0; r < 4; r++) {
      int lin = tid + r*256;
      int nn = lin & 63, kk = lin >> 6;
      int gn = n0 + nn, gk = k0 + kk;
      sB[kk][nn] = (gn < N && gk < K) ? ldin(Bw, bB + (long)gk*ldb + gn, isbf) : 0.f;
    }
    __syncthreads();
#pragma unroll
    for (int kk = 0; kk < 16; kk++) {
      const float4 a4 = *(const float4*)(&sA[kk][ty*4]);
      const float4 b4 = *(const float4*)(&sB[kk][tx*4]);
      float av[4] = {a4.x, a4.y, a4.z, a4.w};
      float bv[4] = {b4.x, b4.y, b4.z, b4.w};
#pragma unroll
      for (int i=0;i<4;i++)
#pragma unroll
        for (int j=0;j<4;j++) acc[i][j] += av[i]*bv[j];
    }
    __syncthreads();
  }
#pragma unroll
  for (int i=0;i<4;i++) {
    const int gm = m0 + ty*4 + i;
    if (gm >= M) continue;
#pragma unroll
    for (int j=0;j<4;j++) {
      const int gn = n0 + tx*4 + j;
      if (gn >= N) continue;
      float vv = acc[i][j]*alpha;
      if (flags & 1) vv += ldin(bias, bBias + gn, isbf);
      if (flags & 4) vv = geluf(vv);
      const long idx = cBase + (long)gm*ldc + gn;
      if (flags & 8) {
        ((unsigned short*)C)[idx] = f2bu(vv);
      } else {
        if (flags & 2) vv += C[idx];
        C[idx] = vv;
      }
    }
  }
}

// ---------------- sLSTM scan v4: 512 threads, 2 threads per (gate,e), 32 wts/thread ----------------
// tid = g*128 + e*2 + half ; partial dots combined via __shfl_xor(r,1)
__global__ __launch_bounds__(512, 1) void slstm_scan4(
    const float* __restrict__ g4, const float* __restrict__ wR,
    float* __restrict__ hs)
{
  const int blk = blockIdx.x;
  const int b = blk >> 3, hd = blk & 7;
  const int tid = threadIdx.x;
  const int g = tid >> 7;          // 0..3
  const int e = (tid >> 1) & 63;   // 0..63
  const int half = tid & 1;

  float4 w[8];   // 32 weights in VGPRs
  {
    const float* p = wR + (((long)g*8 + hd)*64 + e)*64 + half*32;
#pragma unroll
    for (int d4 = 0; d4 < 8; d4++) w[d4] = *(const float4*)(p + d4*4);
  }

  __shared__ float hlds[64];
  __shared__ float rec[4][64];
  if (tid < 64) hlds[tid] = 0.f;
  float c = 0.f, n = 0.f, m = 0.f;
  __syncthreads();

  const long gbase = (long)g*BT_*D_ + (long)(b*T_)*D_ + hd*64 + e;
  float gnext = (half == 0) ? g4[gbase] : 0.f;

  for (int t = 0; t < T_; t++) {
    const float gc = gnext;
    if (half == 0 && t+1 < T_) gnext = g4[gbase + (long)(t+1)*D_];
    float r = 0.f;
    const float* hb = &hlds[half*32];
#pragma unroll
    for (int d4 = 0; d4 < 8; d4++) {
      const float4 hv = *(const float4*)(hb + d4*4);
      r += w[d4].x*hv.x + w[d4].y*hv.y + w[d4].z*hv.z + w[d4].w*hv.w;
    }
    r += __shfl_xor(r, 1);     // combine the two halves (adjacent lanes)
    if (half == 0) {
      r += gc;
      if (g == 2) r = tanhf(r);
      else if (g == 3) r = 1.f/(1.f+expf(-r));
      rec[g][e] = r;
    }
    __syncthreads();
    if (tid < 64) {
      const int es = tid;
      const float it = rec[0][es], ft = rec[1][es];
      const float zt = rec[2][es];
      const float ot = rec[3][es];
      const float mn = fmaxf(ft + m, it);
      const float ig = expf(it - mn);
      const float fg = expf(ft + m - mn);
      c = fg*c + ig*zt;
      n = fg*n + ig;
      m = mn;
      const float hn = ot*c/fmaxf(n, 1e-6f);
      hlds[es] = hn;
      hs[(long)(b*T_+t)*D_ + hd*64 + es] = hn;
    }
    __syncthreads();
  }
}

// ---------------- sLSTM scan (fallback, reads raw Rg) ----------------
__global__ __launch_bounds__(256) void slstm_scan(
    const float* __restrict__ g4, const void* __restrict__ Rg, long offR,
    float* __restrict__ hs, const int* __restrict__ dflag)
{
  const int isbf = *dflag;
  const int blk = blockIdx.x;
  const int b = blk >> 3, hd = blk & 7;
  const int tid = threadIdx.x;
  const int g = tid >> 6, e = tid & 63;
  float w[64];
  {
    const long wp = offR + ((long)(g*NH_ + hd)*64)*64 + e;
#pragma unroll
    for (int d = 0; d < 64; d++) w[d] = ldin(Rg, wp + d*64, isbf);
  }
  __shared__ float hlds[64];
  __shared__ float rec[4][64];
  if (tid < 64) hlds[tid] = 0.f;
  float c = 0.f, n = 0.f, m = 0.f;
  __syncthreads();
  const long gate_base = (long)(b*T_)*D_ + hd*64 + e;
  for (int t = 0; t < T_; t++) {
    float r = 0.f;
#pragma unroll
    for (int d4 = 0; d4 < 16; d4++) {
      const float4 hv = *(const float4*)(&hlds[d4*4]);
      r += w[4*d4]*hv.x + w[4*d4+1]*hv.y + w[4*d4+2]*hv.z + w[4*d4+3]*hv.w;
    }
    r += g4[(long)g*BT_*D_ + gate_base + (long)t*D_];
    rec[g][e] = r;
    __syncthreads();
    if (tid < 64) {
      const float it = rec[0][e], ft = rec[1][e];
      const float zt = tanhf(rec[2][e]);
      const float ot = 1.f/(1.f+expf(-rec[3][e]));
      const float mn = fmaxf(ft + m, it);
      const float ig = expf(it - mn);
      const float fg = expf(ft + m - mn);
      c = fg*c + ig*zt;
      n = fg*n + ig;
      m = mn;
      const float hn = ot*c/fmaxf(n, 1e-6f);
      hlds[e] = hn;
      hs[(long)(b*T_+t)*D_ + hd*64 + e] = hn;
    }
    __syncthreads();
  }
}

// ---------------- head_norm(dh=64) * gn, accumulated into h ----------------
__global__ __launch_bounds__(64) void hn_add(
    const float* __restrict__ hs, const void* __restrict__ gn, long offG,
    float* __restrict__ h, const int* __restrict__ dflag)
{
  const int isbf = *dflag;
  const int blk = blockIdx.x;
  const int bt = blk >> 3, hd = blk & 7;
  const int e = threadIdx.x;
  const long idx = (long)bt*D_ + hd*64 + e;
  const float x = hs[idx];
  float s1 = x, s2 = x*x;
#pragma unroll
  for (int o = 32; o > 0; o >>= 1) { s1 += __shfl_xor(s1, o); s2 += __shfl_xor(s2, o); }
  const float mu = s1*(1.f/64.f);
  const float var = s2*(1.f/64.f) - mu*mu;
  const float y = (x-mu)*rsqrtf(var+EPS_)*ldin(gn, offG + hd*64+e, isbf);
  h[idx] += y;
}

// ---------------- FF gating: gelu(g)*up, written with 704 stride (zero pad) ----------------
__global__ void ffgate(const float* __restrict__ u, float* __restrict__ out)
{
  const long total = (long)BT_*FFP_;
  for (long idx = (long)blockIdx.x*256 + threadIdx.x; idx < total;
       idx += (long)gridDim.x*256) {
    const long m = idx / FFP_;
    const int j = (int)(idx % FFP_);
    float r = 0.f;
    if (j < FF_) {
      const float g = u[m*FF2_ + j];
      r = geluf(g) * u[m*FF2_ + FF_ + j];
    }
    out[idx] = r;
  }
}

// ---------------- mLSTM gate cumsum: one block per (b, head) ----------------
__global__ __launch_bounds__(256) void mlstm_cf(
    const float* __restrict__ g16, float* __restrict__ cf, float* __restrict__ logi)
{
  const int bh = blockIdx.x;
  const int b = bh >> 3, hd = bh & 7;
  const int tid = threadIdx.x;
  __shared__ float slf[T_];
  if (tid < T_) {
    const float gf = g16[(long)(b*T_+tid)*16 + 8 + hd];
    const float ls = (gf >= 0.f) ? -log1pf(expf(-gf)) : (gf - log1pf(expf(gf)));
    slf[tid] = ls;
    logi[(long)bh*T_ + tid] = g16[(long)(b*T_+tid)*16 + hd];
  }
  __syncthreads();
  if (tid == 0) {
    float a = 0.f;
    for (int t = 0; t < T_; t++) { a += slf[t]; slf[t] = a; }
  }
  __syncthreads();
  if (tid < T_) cf[(long)bh*T_ + tid] = slf[tid];
}

// ---------------- MFMA flash attention ----------------
#define QPD 136
#define VPD 72
__global__ __launch_bounds__(256) void attn_mfma(
    const float* __restrict__ q, const unsigned short* __restrict__ k,
    const unsigned short* __restrict__ v, const float* __restrict__ cf,
    const float* __restrict__ li, float* __restrict__ hatt)
{
  const int tt = blockIdx.x, bh = blockIdx.y;
  const int b = bh >> 3, hd = bh & 7;
  const int t0 = tt*64;
  const int tid = threadIdx.x;
  const int w = tid >> 6, lane = tid & 63;
  const int lr = lane & 15, lq = lane >> 4;

  __shared__ unsigned short sQ[64*QPD];
  __shared__ unsigned short sK[64*QPD];
  __shared__ unsigned short sVt[128*VPD];
  __shared__ unsigned short sS[64*VPD];
  __shared__ float scft[64], scfs[64], slis[64];

  for (int idx = tid; idx < 64*64; idx += 256){
    int r = idx >> 6, dp = idx & 63;
    int t = t0 + r;
    unsigned pk = 0;
    if (t < T_){
      const float* qp = q + ((long)(b*T_+t))*DI_ + hd*DHI_ + dp*2;
      pk = packbf(qp[0], qp[1]);
    }
    *(unsigned*)&sQ[r*QPD + dp*2] = pk;
  }
  if (tid < 64) scft[tid] = (t0+tid < T_) ? cf[(long)bh*T_ + t0+tid] : 0.f;

  float m_st[4], s_st[4], alpha_[4];
#pragma unroll
  for (int rr=0;rr<4;rr++){ m_st[rr] = -INFINITY; s_st[rr] = 0.f; }
  floatx4 accO[8];
#pragma unroll
  for (int nd=0;nd<8;nd++)
#pragma unroll
    for (int rr=0;rr<4;rr++) accO[nd][rr] = 0.f;

  for (int st = 0; st <= tt; st++){
    const int s0 = st*64;
    for (int idx = tid; idx < 64*64; idx += 256){
      int r = idx >> 6, dp = idx & 63;
      int s = s0 + r;
      unsigned pkk = 0, pkv = 0;
      if (s < T_){
        const long base = ((long)(b*T_+s))*DI_ + hd*DHI_ + dp*2;
        pkk = *(const unsigned*)&k[base];
        pkv = *(const unsigned*)&v[base];
      }
      *(unsigned*)&sK[r*QPD + dp*2] = pkk;
      sVt[(dp*2)*VPD + r]   = (unsigned short)(pkv & 0xFFFFu);
      sVt[(dp*2+1)*VPD + r] = (unsigned short)(pkv >> 16);
    }
    if (tid < 64){
      int s = s0 + tid;
      scfs[tid] = (s < T_) ? cf[(long)bh*T_ + s] : 0.f;
      slis[tid] = (s < T_) ? li[(long)bh*T_ + s] : 0.f;
    }
    __syncthreads();

    floatx4 accS[4];
#pragma unroll
    for (int ni=0;ni<4;ni++)
#pragma unroll
      for (int rr=0;rr<4;rr++) accS[ni][rr] = 0.f;
    const int qrow = w*16 + lr;
#pragma unroll
    for (int k0=0;k0<4;k0++){
      short8 a = *(const short8*)&sQ[qrow*QPD + k0*32 + lq*8];
#pragma unroll
      for (int ni=0;ni<4;ni++){
        short8 bb = *(const short8*)&sK[(ni*16+lr)*QPD + k0*32 + lq*8];
        accS[ni] = __builtin_amdgcn_mfma_f32_16x16x32_bf16(a, bb, accS[ni], 0,0,0);
      }
    }

#pragma unroll
    for (int rr=0;rr<4;rr++){
      const int tg = t0 + w*16 + lq*4 + rr;
      const float cftr = scft[w*16 + lq*4 + rr];
      float dmv[4];
      float mx = -INFINITY;
#pragma unroll
      for (int ni=0;ni<4;ni++){
        const int sg = s0 + ni*16 + lr;
        const bool valid = (tg < T_) && (sg <= tg);
        dmv[ni] = valid ? (cftr - scfs[ni*16+lr] + slis[ni*16+lr]) : -INFINITY;
        mx = fmaxf(mx, dmv[ni]);
      }
      mx = fmaxf(mx, __shfl_xor(mx, 1));
      mx = fmaxf(mx, __shfl_xor(mx, 2));
      mx = fmaxf(mx, __shfl_xor(mx, 4));
      mx = fmaxf(mx, __shfl_xor(mx, 8));
      const float mnew = fmaxf(m_st[rr], mx);
      const float al = (mnew == -INFINITY) ? 0.f : expf(m_st[rr] - mnew);
      float rs = 0.f;
#pragma unroll
      for (int ni=0;ni<4;ni++){
        const float wexp = (dmv[ni] == -INFINITY) ? 0.f : expf(dmv[ni] - mnew);
        const float pv = accS[ni][rr]*wexp;
        rs += pv;
        sS[(w*16 + lq*4 + rr)*VPD + ni*16 + lr] = f2bu(pv);
      }
      rs += __shfl_xor(rs, 1);
      rs += __shfl_xor(rs, 2);
      rs += __shfl_xor(rs, 4);
      rs += __shfl_xor(rs, 8);
      s_st[rr] = s_st[rr]*al + rs;
      m_st[rr] = mnew;
      alpha_[rr] = al;
    }

#pragma unroll
    for (int nd=0;nd<8;nd++)
#pragma unroll
      for (int rr=0;rr<4;rr++) accO[nd][rr] *= alpha_[rr];

#pragma unroll
    for (int ks=0;ks<2;ks++){
      short8 aP = *(const short8*)&sS[(w*16 + lr)*VPD + ks*32 + lq*8];
#pragma unroll
      for (int nd=0;nd<8;nd++){
        short8 bV = *(const short8*)&sVt[(nd*16+lr)*VPD + ks*32 + lq*8];
        accO[nd] = __builtin_amdgcn_mfma_f32_16x16x32_bf16(aP, bV, accO[nd], 0,0,0);
      }
    }
    __syncthreads();
  }

#pragma unroll
  for (int rr=0;rr<4;rr++){
    const int tg = t0 + w*16 + lq*4 + rr;
    if (tg >= T_) continue;
    const float inv = 1.f / fmaxf(fabsf(s_st[rr]), expf(-m_st[rr]));
    float* op = hatt + ((long)(b*T_+tg))*DI_ + hd*DHI_;
#pragma unroll
    for (int nd=0;nd<8;nd++)
      op[nd*16 + lr] = accO[nd][rr]*inv;
  }
}

// ---------------- head_norm(dh=128)*gn + skip*xc, then *silu(z) ----------------
__global__ __launch_bounds__(128) void hn_mlstm(
    const float* __restrict__ hatt, const void* __restrict__ gn, long offG,
    const void* __restrict__ skip, long offSk, const float* __restrict__ xc,
    const float* __restrict__ u, float* __restrict__ gin,
    const int* __restrict__ dflag)
{
  const int isbf = *dflag;
  const int blk = blockIdx.x;
  const int bt = blk >> 3, hd = blk & 7;
  const int e = threadIdx.x;
  const int j = hd*DHI_ + e;
  const long idx = (long)bt*DI_ + j;
  const float x = hatt[idx];
  __shared__ float r1[128], r2[128];
  r1[e]=x; r2[e]=x*x; __syncthreads();
  for (int o=64;o>0;o>>=1){ if(e<o){r1[e]+=r1[e+o]; r2[e]+=r2[e+o];} __syncthreads(); }
  const float mu = r1[0]*(1.f/128.f);
  const float var = r2[0]*(1.f/128.f)-mu*mu;
  const float y = (x-mu)*rsqrtf(var+EPS_)*ldin(gn, offG+j, isbf) + ldin(skip, offSk+j, isbf)*xc[idx];
  const float z = u[(long)bt*2048 + DI_ + j];
  gin[idx] = y * siluf(z);
}

// ---------------- final transpose to output ----------------
__global__ void out_transpose(const float* __restrict__ hp, void* __restrict__ out,
                              const int* __restrict__ dflag)
{
  const int isbf = *dflag;
  const int tid = threadIdx.x;
  if (tid < B_*6) {
    const int b = tid / 6, hd = tid % 6;
    const float v = hp[hd*B_ + b];
    if (isbf) ((bf16*)out)[tid] = __float2bfloat16(v);
    else      ((float*)out)[tid] = v;
  }
}

extern "C" void kernel_launch(void* const* d_in, const int* in_sizes, int n_in,
                              void* d_out, int out_size, void* d_ws, size_t ws_size,
                              hipStream_t stream)
{
  (void)in_sizes; (void)n_in; (void)out_size;
  const void* x        = d_in[0];
  const void* w_in     = d_in[1];
  const void* b_in     = d_in[2];
  const void* ln_in_s  = d_in[3];
  const void* ln_in_b  = d_in[4];
  const void* s_ln_s   = d_in[5];
  const void* s_ln_b   = d_in[6];
  const void* s_conv_w = d_in[7];
  const void* s_conv_b = d_in[8];
  const void* s_wg     = d_in[9];
  const void* s_rg     = d_in[10];
  const void* s_bg     = d_in[11];
  const void* s_gn     = d_in[12];
  const void* s_ffln_s = d_in[13];
  const void* s_ffln_b = d_in[14];
  const void* s_ff_w1  = d_in[15];
  const void* s_ff_w2  = d_in[16];
  const void* m_ln_s   = d_in[17];
  const void* m_ln_b   = d_in[18];
  const void* m_w_up   = d_in[19];
  const void* m_conv_w = d_in[20];
  const void* m_conv_b = d_in[21];
  const void* m_wq     = d_in[22];
  const void* m_wk     = d_in[23];
  const void* m_wv     = d_in[24];
  const void* m_w_if   = d_in[25];
  const void* m_b_if   = d_in[26];
  const void* m_skip   = d_in[27];
  const void* m_gn     = d_in[28];
  const void* m_w_down = d_in[29];
  const void* post_ln_s= d_in[30];
  const void* post_ln_b= d_in[31];
  const void* hw1      = d_in[32];
  const void* hb1      = d_in[33];
  const void* hw2      = d_in[34];
  const void* hb2      = d_in[35];
  const void* hw3      = d_in[36];
  const void* hb3      = d_in[37];

  float* W   = (float*)d_ws;
  float* h   = W;                           // BT*D
  float* xn  = W + 4128768L;                // BT*D
  float* xc  = W + 8257536L;                // BT*DI
  float* u   = W + 16515072L;               // 4*BT*D
  float* q   = W + 33030144L;               // BT*DI fp32 (hs / ffg(704) / hatt / gin)
  unsigned short* kk_ = (unsigned short*)(W + 41287680L); // BT*DI bf16
  unsigned short* vv_ = (unsigned short*)(W + 45416448L); // BT*DI bf16
  float* g16 = W + 49545216L;               // BT*16
  float* cfb = W + 49674240L;               // B*NH*T
  float* lib = W + 49738752L;               // B*NH*T
  float* last= W + 49803264L;               // 32*512
  float* ha1 = W + 49819648L;               // 6*32*256
  float* ha2 = W + 49868800L;               // 6*32*128
  float* hp  = W + 49893376L;               // 6*32 (pad)
  int*   dfl = (int*)(W + 49893568L);
  float* wsRg = W + 49893632L;              // 4 layers x 4x8x64x64 fp32 = 524288 floats

  // bf16 weight planes (hi, lo), each PLANE ushorts, k-contiguous [N][K]
  const long PLANE = 14327808L;
  unsigned short* wtHi = (unsigned short*)(W + 50417920L);
  unsigned short* wtLo = wtHi + PLANE;
  const long oWg=0, oF1=4194304L, oF2=6987776L, oUp=8429568L;
  const long oQ=11575296L, oK=11968512L, oV=12361728L, oDn=12754944L;

  const size_t needFull = (size_t)(50417920L + PLANE)*4;            // ~259.0 MB
  const size_t needMid  = (size_t)(50417920L + PLANE/2)*4 + PLANE;  // tier1: hi plane only
  const int tier = (ws_size >= needFull) ? 2 : ((ws_size >= needMid) ? 1 : 0);
  const int spB = (tier == 2) ? 1 : 0;
  unsigned short* loArg = (tier == 2) ? wtLo : nullptr;

  const float kscale = 0.08838834764831845f; // 1/sqrt(128)

  detect_dtype<<<1, 64, 0, stream>>>((const unsigned*)ln_in_s, dfl);

  if (tier >= 1) {
    rg_prep<<<128, 256, 0, stream>>>(s_rg, wsRg, dfl);
    wt_transpose2<<<dim3(16,16,16),256,0,stream>>>(s_wg, 0, 262144L, 512, 512, 512,
        wtHi+oWg, loArg?loArg+oWg:nullptr, 262144L, dfl);
    wt_transpose2<<<dim3(43,16,4),256,0,stream>>>(s_ff_w1, 0, 698368L, 512, 1364, 512,
        wtHi+oF1, loArg?loArg+oF1:nullptr, 698368L, dfl);
    wt_transpose2<<<dim3(16,22,4),256,0,stream>>>(s_ff_w2, 0, 349184L, 682, 512, 704,
        wtHi+oF2, loArg?loArg+oF2:nullptr, 360448L, dfl);
    wt_transpose2<<<dim3(64,16,3),256,0,stream>>>(m_w_up, 0, 1048576L, 512, 2048, 512,
        wtHi+oUp, loArg?loArg+oUp:nullptr, 1048576L, dfl);
    wt_transpose2<<<dim3(4,4,24),256,0,stream>>>(m_wq, 0, 16384L, 128, 128, 128,
        wtHi+oQ, loArg?loArg+oQ:nullptr, 16384L, dfl);
    wt_transpose2<<<dim3(4,4,24),256,0,stream>>>(m_wk, 0, 16384L, 128, 128, 128,
        wtHi+oK, loArg?loArg+oK:nullptr, 16384L, dfl);
    wt_transpose2<<<dim3(4,4,24),256,0,stream>>>(m_wv, 0, 16384L, 128, 128, 128,
        wtHi+oV, loArg?loArg+oV:nullptr, 16384L, dfl);
    wt_transpose2<<<dim3(16,32,3),256,0,stream>>>(m_w_down, 0, 524288L, 1024, 512, 1024,
        wtHi+oDn, loArg?loArg+oDn:nullptr, 524288L, dfl);
  }

  ln_proj<<<BT_, 256, 0, stream>>>(x, w_in, b_in, ln_in_s, ln_in_b, h, dfl);

  int si = 0, mi = 0;
  for (int blk = 0; blk < 7; blk++) {
    if ((blk & 1) == 0) {
      // ---- sLSTM block ----
      ln_rows<<<BT_,256,0,stream>>>(h, 512L, s_ln_s, (long)si*512, s_ln_b, (long)si*512, xn, dfl);
      {
        long tot = (long)BT_*512; int g = (int)((tot+255)/256);
        conv_silu<<<g,256,0,stream>>>(xn, 512, s_conv_w, (long)si*4*512, s_conv_b, (long)si*512, xc, 512, dfl);
      }
      if (tier >= 1) {
        gemm_split<<<dim3(8,126,4),256,0,stream>>>(xc, xn, 2, 0L,
            wtHi+oWg+(long)si*4*262144L, wtLo+oWg+(long)si*4*262144L,
            s_bg, (long)si*4*512, u,
            512, 512, 512, 512, 262144L, (long)BT_*512, 512L, 1.f, 1, spB, dfl);
      } else {
        for (int g = 0; g < 4; g++) {
          const float* Ain = (g < 2) ? xc : xn;
          gemm_f32b<<<dim3(8,126,1),256,0,stream>>>(Ain, s_wg, ((long)(si*4+g))*512*512,
              s_bg, (long)(si*4+g)*512, u + (long)g*BT_*512,
              BT_, 512, 512, 512, 512, 512, 0,0,0,0, 1.f, 1, dfl);
        }
      }
      if (tier >= 1)
        slstm_scan4<<<256,512,0,stream>>>(u, wsRg + (long)si*131072L, q /*hs*/);
      else
        slstm_scan<<<256,256,0,stream>>>(u, s_rg, (long)si*4*8*64*64, q /*hs*/, dfl);
      hn_add<<<BT_*8,64,0,stream>>>(q, s_gn, (long)si*512, h, dfl);
      // ---- FF block ----
      ln_rows<<<BT_,256,0,stream>>>(h, 512L, s_ffln_s, (long)si*512, s_ffln_b, (long)si*512, xn, dfl);
      if (tier >= 1)
        gemm_split<<<dim3(22,126,1),256,0,stream>>>(xn, xn, 9, 0L,
            wtHi+oF1+(long)si*698368L, wtLo+oF1+(long)si*698368L, nullptr, 0,
            u, 1364, 512, 512, 1364, 0,0,0, 1.f, 0, spB, dfl);
      else
        gemm_f32b<<<dim3(22,126,1),256,0,stream>>>(xn, s_ff_w1, (long)si*512*1364, nullptr, 0,
            u, BT_, 1364, 512, 512, 1364, 1364, 0,0,0,0, 1.f, 0, dfl);
      {
        long tot = (long)BT_*FFP_; int g = (int)((tot+255)/256);
        ffgate<<<g,256,0,stream>>>(u, q /*ffg, stride 704*/);
      }
      if (tier >= 1)
        gemm_split<<<dim3(8,126,1),256,0,stream>>>(q, q, 9, 0L,
            wtHi+oF2+(long)si*360448L, wtLo+oF2+(long)si*360448L, nullptr, 0,
            h, 512, 704, 704, 512, 0,0,0, 1.f, 2, spB, dfl);
      else
        gemm_f32b<<<dim3(8,126,1),256,0,stream>>>(q, s_ff_w2, (long)si*682*512, nullptr, 0,
            h, BT_, 512, 682, 704, 512, 512, 0,0,0,0, 1.f, 2, dfl);
      si++;
    } else {
      // ---- mLSTM block ----
      ln_rows<<<BT_,256,0,stream>>>(h, 512L, m_ln_s, (long)mi*512, m_ln_b, (long)mi*512, xn, dfl);
      if (tier >= 1)
        gemm_split<<<dim3(32,126,1),256,0,stream>>>(xn, xn, 9, 0L,
            wtHi+oUp+(long)mi*1048576L, wtLo+oUp+(long)mi*1048576L, nullptr, 0,
            u, 2048, 512, 512, 2048, 0,0,0, 1.f, 0, spB, dfl);
      else
        gemm_f32b<<<dim3(32,126,1),256,0,stream>>>(xn, m_w_up, (long)mi*512*2048, nullptr, 0,
            u, BT_, 2048, 512, 512, 2048, 2048, 0,0,0,0, 1.f, 0, dfl);
      {
        long tot = (long)BT_*1024; int g = (int)((tot+255)/256);
        conv_silu<<<g,256,0,stream>>>(u, 2048, m_conv_w, (long)mi*4*1024, m_conv_b, (long)mi*1024, xc, 1024, dfl);
      }
      if (tier >= 1) {
        gemm_split<<<dim3(2,126,8),256,0,stream>>>(xc, xc, 9, 128L,
            wtHi+oQ+(long)mi*131072L, wtLo+oQ+(long)mi*131072L, nullptr, 0,
            q, 128, 128, 1024, 1024, 16384L, 128L, 0, 1.f, 0, spB, dfl);
        gemm_split<<<dim3(2,126,8),256,0,stream>>>(xc, xc, 9, 128L,
            wtHi+oK+(long)mi*131072L, wtLo+oK+(long)mi*131072L, nullptr, 0,
            (float*)kk_, 128, 128, 1024, 1024, 16384L, 128L, 0, kscale, 8, spB, dfl);
        gemm_split<<<dim3(2,126,8),256,0,stream>>>(u, u, 9, 128L,
            wtHi+oV+(long)mi*131072L, wtLo+oV+(long)mi*131072L, nullptr, 0,
            (float*)vv_, 128, 128, 2048, 1024, 16384L, 128L, 0, 1.f, 8, spB, dfl);
      } else {
        gemm_f32b<<<dim3(2,126,8),256,0,stream>>>(xc, m_wq, (long)mi*8*128*128, nullptr, 0,
            q, BT_, 128, 128, 1024, 128, 1024, 128, 16384, 128, 0, 1.f, 0, dfl);
        gemm_f32b<<<dim3(2,126,8),256,0,stream>>>(xc, m_wk, (long)mi*8*128*128, nullptr, 0,
            (float*)kk_, BT_, 128, 128, 1024, 128, 1024, 128, 16384, 128, 0, kscale, 8, dfl);
        gemm_f32b<<<dim3(2,126,8),256,0,stream>>>(u, m_wv, (long)mi*8*128*128, nullptr, 0,
            (float*)vv_, BT_, 128, 128, 2048, 128, 1024, 128, 16384, 128, 0, 1.f, 8, dfl);
      }
      gemm_f32b<<<dim3(1,126,1),256,0,stream>>>(xc, m_w_if, (long)mi*1024*16, m_b_if, (long)mi*16,
            g16, BT_, 16, 1024, 1024, 16, 16, 0,0,0,0, 1.f, 1, dfl);
      mlstm_cf<<<256,256,0,stream>>>(g16, cfb, lib);
      attn_mfma<<<dim3(4,256),256,0,stream>>>(q, kk_, vv_, cfb, lib, q /*hatt in-place*/);
      hn_mlstm<<<BT_*8,128,0,stream>>>(q, m_gn, (long)mi*1024, m_skip, (long)mi*1024, xc, u, q, dfl);
      if (tier >= 1)
        gemm_split<<<dim3(8,126,1),256,0,stream>>>(q, q, 9, 0L,
            wtHi+oDn+(long)mi*524288L, wtLo+oDn+(long)mi*524288L, nullptr, 0,
            h, 512, 1024, 1024, 512, 0,0,0, 1.f, 2, spB, dfl);
      else
        gemm_f32b<<<dim3(8,126,1),256,0,stream>>>(q, m_w_down, (long)mi*1024*512, nullptr, 0,
            h, BT_, 512, 1024, 1024, 512, 512, 0,0,0,0, 1.f, 2, dfl);
      mi++;
    }
  }

  // post-LN on last timestep rows only
  ln_rows<<<B_,256,0,stream>>>(h + (long)(T_-1)*512, (long)T_*512, post_ln_s, 0, post_ln_b, 0, last, dfl);

  // 6 prediction heads, batched over grid.z (tiny; SIMT fp32)
  gemm_f32b<<<dim3(4,1,6),256,0,stream>>>(last, hw1, 0, hb1, 0, ha1, 32, 256, 512, 512, 256, 256,
        0, 512L*256, 32L*256, 256, 1.f, 1|4, dfl);
  gemm_f32b<<<dim3(2,1,6),256,0,stream>>>(ha1, hw2, 0, hb2, 0, ha2, 32, 128, 256, 256, 128, 128,
        32L*256, 256L*128, 32L*128, 128, 1.f, 1|4, dfl);
  gemm_f32b<<<dim3(1,1,6),256,0,stream>>>(ha2, hw3, 0, hb3, 0, hp, 32, 1, 128, 128, 1, 1,
        32L*128, 128L, 32L, 1, 1.f, 1, dfl);
  out_transpose<<<1,256,0,stream>>>(hp, d_out, dfl);
}

// Round 10
// 3530.904 us; speedup vs baseline: 1.2067x; 1.1108x over previous
//
#include <hip/hip_runtime.h>
#include <hip/hip_bf16.h>
#include <cmath>

typedef __hip_bfloat16 bf16;

#define B_   32
#define T_   252
#define F_   8
#define D_   512
#define NH_  8
#define DH_  64
#define DI_  1024
#define DHI_ 128
#define FF_  682
#define FF2_ 1364
#define FFP_ 704
#define BT_  (B_*T_)
#define EPS_ 1e-5f

typedef __attribute__((ext_vector_type(8))) short short8;
typedef __attribute__((ext_vector_type(4))) float floatx4;

__device__ __forceinline__ float b2f(bf16 v){ return __bfloat162float(v); }
__device__ __forceinline__ float siluf(float x){ return x/(1.f+expf(-x)); }
__device__ __forceinline__ float geluf(float x){
  float x3 = x*x*x;
  return 0.5f*x*(1.f+tanhf(0.7978845608028654f*(x+0.044715f*x3)));
}
__device__ __forceinline__ float ldin(const void* p, long i, int isbf){
  return isbf ? __bfloat162float(((const bf16*)p)[i]) : ((const float*)p)[i];
}
__device__ __forceinline__ unsigned short f2bu(float f){
  bf16 h = __float2bfloat16(f);
  return *(reinterpret_cast<unsigned short*>(&h));
}
__device__ __forceinline__ void split2(float v, unsigned short& h, unsigned short& l){
  bf16 hb = __float2bfloat16(v);
  h = *(reinterpret_cast<unsigned short*>(&hb));
  float r = v - __bfloat162float(hb);
  bf16 lb = __float2bfloat16(r);
  l = *(reinterpret_cast<unsigned short*>(&lb));
}
__device__ __forceinline__ unsigned packbf(float x, float y){
  return (unsigned)f2bu(x) | ((unsigned)f2bu(y) << 16);
}

__global__ void detect_dtype(const unsigned* __restrict__ probe, int* __restrict__ flag)
{
  if (threadIdx.x == 0) *flag = (*probe == 0x3F803F80u) ? 1 : 0;
}

// ---- sLSTM recurrent weight prep: Rg [si][g][hd][d][e] -> fp32 [(si*4+g)*8+hd][e][d] ----
__global__ __launch_bounds__(256) void rg_prep(
    const void* __restrict__ Rg, float* __restrict__ out, const int* __restrict__ dflag)
{
  const int isbf = *dflag;
  const int c = blockIdx.x;          // 0..127 = (si*4+g)*8+hd
  const long base = (long)c*4096;
  __shared__ float tl[64][65];
  const int col = threadIdx.x & 63, r4 = threadIdx.x >> 6;
#pragma unroll
  for (int i=0;i<16;i++){
    int d = i*4 + r4;
    tl[d][col] = ldin(Rg, base + (long)d*64 + col, isbf);
  }
  __syncthreads();
#pragma unroll
  for (int i=0;i<16;i++){
    int e = i*4 + r4;
    out[base + (long)e*64 + col] = tl[col][e];
  }
}

// ---- weight transpose + hi/lo bf16 split: in [K][N] -> planes [N][outK] (outK>=K zero-pad) ----
__global__ __launch_bounds__(256) void wt_transpose2(
    const void* __restrict__ in, long inOff, long inStride, int K, int N, int outK,
    unsigned short* __restrict__ outHi, unsigned short* __restrict__ outLo,
    long outStride, const int* __restrict__ dflag)
{
  const int isbf = *dflag;
  const int bz = blockIdx.z;
  const long base = inOff + (long)bz*inStride;
  unsigned short* oh = outHi + (long)bz*outStride;
  unsigned short* ol = outLo ? outLo + (long)bz*outStride : nullptr;
  __shared__ float tile[32][33];
  const int k0 = blockIdx.y*32, n0 = blockIdx.x*32;
  const int tn = threadIdx.x & 31, tk = threadIdx.x >> 5;
#pragma unroll
  for (int i=0;i<4;i++){
    int kk = tk + i*8;
    float v = 0.f;
    if (k0+kk < K && n0+tn < N) v = ldin(in, base + (long)(k0+kk)*N + n0+tn, isbf);
    tile[kk][tn] = v;
  }
  __syncthreads();
#pragma unroll
  for (int i=0;i<4;i++){
    int nn = tk + i*8;
    if (n0+nn < N && k0+tn < outK){
      unsigned short h, l;
      split2(tile[tn][nn], h, l);
      oh[(long)(n0+nn)*outK + k0+tn] = h;
      if (ol) ol[(long)(n0+nn)*outK + k0+tn] = l;
    }
  }
}

// ---- split-bf16 MFMA GEMM: C = alpha*(A@B) [+bias] [+C] ----
// flags: 1=bias, 2=accumulate, 8=store C as packed bf16 (ushort)
__global__ __launch_bounds__(256) void gemm_split(
    const float* __restrict__ A0, const float* __restrict__ A1, int zSplit, long strideA,
    const unsigned short* __restrict__ Bhi, const unsigned short* __restrict__ Blo,
    const void* __restrict__ bias, long offBias, float* __restrict__ C,
    int N, int K, int lda, int ldc,
    long strideBT, long strideC, long strideBias,
    float alpha, int flags, int splitB, const int* __restrict__ dflag)
{
  const int isbf = *dflag;
  const int bz = blockIdx.z;
  const float* A = ((bz < zSplit) ? A0 : A1) + (long)bz*strideA;
  const unsigned short* bhp = Bhi + (long)bz*strideBT;
  const unsigned short* blp = Blo + (long)bz*strideBT;
  const long cBase = (long)bz*strideC;
  const long bBias = offBias + (long)bz*strideBias;

  __shared__ unsigned short aH[64*72], aL[64*72], bH[64*72], bL[64*72];
  const int tid = threadIdx.x;
  const int wid = tid >> 6, lane = tid & 63;
  const int wm = (wid >> 1)*32, wn = (wid & 1)*32;
  const int m0 = blockIdx.y*64, n0 = blockIdx.x*64;
  const int lr = lane & 15, lq = lane >> 4;

  floatx4 acc[2][2];
#pragma unroll
  for (int mi=0;mi<2;mi++)
#pragma unroll
    for (int ni=0;ni<2;ni++)
#pragma unroll
      for (int r=0;r<4;r++) acc[mi][ni][r] = 0.f;

  const int sRow = tid >> 2;
  const int sSeg = (tid & 3)*16;

  for (int k0 = 0; k0 < K; k0 += 64) {
    {
      const float* ap = A + (long)(m0 + sRow)*lda + k0 + sSeg;
#pragma unroll
      for (int c=0;c<4;c++){
        const float4 v = *(const float4*)(ap + c*4);
        unsigned short h0,h1,h2,h3,l0,l1,l2,l3;
        split2(v.x,h0,l0); split2(v.y,h1,l1); split2(v.z,h2,l2); split2(v.w,h3,l3);
        uint2 ph, pl;
        ph.x = (unsigned)h0 | ((unsigned)h1<<16); ph.y = (unsigned)h2 | ((unsigned)h3<<16);
        pl.x = (unsigned)l0 | ((unsigned)l1<<16); pl.y = (unsigned)l2 | ((unsigned)l3<<16);
        *(uint2*)&aH[sRow*72 + sSeg + c*4] = ph;
        *(uint2*)&aL[sRow*72 + sSeg + c*4] = pl;
      }
    }
    {
      const int gn = n0 + sRow;
      const bool nv = gn < N;
      const long bo = (long)gn*K + k0 + sSeg;
      uint4 z4; z4.x=z4.y=z4.z=z4.w=0;
      uint4 h0 = nv ? *(const uint4*)(bhp + bo)     : z4;
      uint4 h1 = nv ? *(const uint4*)(bhp + bo + 8) : z4;
      *(uint4*)&bH[sRow*72 + sSeg]     = h0;
      *(uint4*)&bH[sRow*72 + sSeg + 8] = h1;
      if (splitB){
        uint4 l0_ = nv ? *(const uint4*)(blp + bo)     : z4;
        uint4 l1_ = nv ? *(const uint4*)(blp + bo + 8) : z4;
        *(uint4*)&bL[sRow*72 + sSeg]     = l0_;
        *(uint4*)&bL[sRow*72 + sSeg + 8] = l1_;
      }
    }
    __syncthreads();

#pragma unroll
    for (int ks=0;ks<2;ks++){
      short8 ah[2], al[2], bh_[2], bl_[2];
#pragma unroll
      for (int mi=0;mi<2;mi++){
        ah[mi] = *(const short8*)&aH[(wm+mi*16+lr)*72 + ks*32 + lq*8];
        al[mi] = *(const short8*)&aL[(wm+mi*16+lr)*72 + ks*32 + lq*8];
      }
#pragma unroll
      for (int ni=0;ni<2;ni++){
        bh_[ni] = *(const short8*)&bH[(wn+ni*16+lr)*72 + ks*32 + lq*8];
        if (splitB) bl_[ni] = *(const short8*)&bL[(wn+ni*16+lr)*72 + ks*32 + lq*8];
      }
#pragma unroll
      for (int mi=0;mi<2;mi++)
#pragma unroll
        for (int ni=0;ni<2;ni++){
          acc[mi][ni] = __builtin_amdgcn_mfma_f32_16x16x32_bf16(al[mi], bh_[ni], acc[mi][ni], 0,0,0);
          if (splitB)
            acc[mi][ni] = __builtin_amdgcn_mfma_f32_16x16x32_bf16(ah[mi], bl_[ni], acc[mi][ni], 0,0,0);
          acc[mi][ni] = __builtin_amdgcn_mfma_f32_16x16x32_bf16(ah[mi], bh_[ni], acc[mi][ni], 0,0,0);
        }
    }
    __syncthreads();
  }

#pragma unroll
  for (int mi=0;mi<2;mi++){
#pragma unroll
    for (int ni=0;ni<2;ni++){
      const int gn = n0 + wn + ni*16 + lr;
      if (gn >= N) continue;
      const float bv = (flags & 1) ? ldin(bias, bBias + gn, isbf) : 0.f;
#pragma unroll
      for (int rr=0;rr<4;rr++){
        const int gm = m0 + wm + mi*16 + lq*4 + rr;
        float vv = acc[mi][ni][rr]*alpha + bv;
        const long idx = cBase + (long)gm*ldc + gn;
        if (flags & 8) {
          ((unsigned short*)C)[idx] = f2bu(vv);
        } else {
          if (flags & 2) vv += C[idx];
          C[idx] = vv;
        }
      }
    }
  }
}

// ---------------- input projection + layernorm ----------------
__global__ __launch_bounds__(256) void ln_proj(
    const void* __restrict__ x, const void* __restrict__ w,
    const void* __restrict__ bb, const void* __restrict__ s,
    const void* __restrict__ b, float* __restrict__ out,
    const int* __restrict__ dflag)
{
  const int isbf = *dflag;
  const int r = blockIdx.x;
  const int tid = threadIdx.x;
  float xr[8];
#pragma unroll
  for (int f = 0; f < 8; f++) xr[f] = ldin(x, (long)r*8+f, isbf);
  float vv[2];
#pragma unroll
  for (int i2 = 0; i2 < 2; i2++) {
    const int j = tid + i2*256;
    float a = ldin(bb, j, isbf);
#pragma unroll
    for (int f = 0; f < 8; f++) a += xr[f]*ldin(w, f*512+j, isbf);
    vv[i2] = a;
  }
  __shared__ float r1[256], r2[256];
  r1[tid] = vv[0]+vv[1]; r2[tid] = vv[0]*vv[0]+vv[1]*vv[1];
  __syncthreads();
  for (int o = 128; o > 0; o >>= 1) {
    if (tid < o) { r1[tid]+=r1[tid+o]; r2[tid]+=r2[tid+o]; }
    __syncthreads();
  }
  const float mu = r1[0]*(1.f/512.f);
  const float var = r2[0]*(1.f/512.f)-mu*mu;
  const float rstd = rsqrtf(var+EPS_);
  float* orow = out + (long)r*512;
#pragma unroll
  for (int i2 = 0; i2 < 2; i2++) {
    const int j = tid + i2*256;
    orow[j] = (vv[i2]-mu)*rstd*ldin(s, j, isbf) + ldin(b, j, isbf);
  }
}

// ---------------- layernorm over 512-elem rows ----------------
__global__ __launch_bounds__(256) void ln_rows(
    const float* __restrict__ in, long rowStride,
    const void* __restrict__ s, long offS,
    const void* __restrict__ b, long offB,
    float* __restrict__ out, const int* __restrict__ dflag)
{
  const int isbf = *dflag;
  const long r = blockIdx.x;
  const int tid = threadIdx.x;
  const float* xr = in + r*rowStride;
  const float v0 = xr[tid], v1 = xr[tid+256];
  __shared__ float r1[256], r2[256];
  r1[tid] = v0+v1; r2[tid] = v0*v0+v1*v1;
  __syncthreads();
  for (int o = 128; o > 0; o >>= 1) {
    if (tid < o) { r1[tid]+=r1[tid+o]; r2[tid]+=r2[tid+o]; }
    __syncthreads();
  }
  const float mu = r1[0]*(1.f/512.f);
  const float var = r2[0]*(1.f/512.f)-mu*mu;
  const float rstd = rsqrtf(var+EPS_);
  float* orow = out + r*(long)D_;
  orow[tid]     = (v0-mu)*rstd*ldin(s, offS+tid, isbf)     + ldin(b, offB+tid, isbf);
  orow[tid+256] = (v1-mu)*rstd*ldin(s, offS+tid+256, isbf) + ldin(b, offB+tid+256, isbf);
}

// ---------------- causal conv(K=4) + silu ----------------
__global__ void conv_silu(const float* __restrict__ in, int inStride,
                          const void* __restrict__ w, long offW,
                          const void* __restrict__ bias, long offBias,
                          float* __restrict__ out, int Dc,
                          const int* __restrict__ dflag)
{
  const int isbf = *dflag;
  const long total = (long)BT_ * Dc;
  for (long idx = (long)blockIdx.x*256 + threadIdx.x; idx < total;
       idx += (long)gridDim.x*256) {
    const int d = (int)(idx % Dc);
    const long bt = idx / Dc;
    const int b = (int)(bt / T_), t = (int)(bt % T_);
    float a = ldin(bias, offBias + d, isbf);
#pragma unroll
    for (int kk = 0; kk < 4; kk++) {
      const int ts = t - 3 + kk;
      if (ts >= 0) a += ldin(w, offW + kk*Dc + d, isbf) * in[((long)(b*T_+ts))*inStride + d];
    }
    out[idx] = siluf(a);
  }
}

// ---------------- fallback SIMT GEMM ----------------
__global__ __launch_bounds__(256) void gemm_f32b(
    const float* __restrict__ A, const void* __restrict__ Bw, long offB,
    const void* __restrict__ bias, long offBias, float* __restrict__ C,
    int M, int N, int K, int lda, int ldb, int ldc,
    long strideA, long strideB, long strideC, long strideBias,
    float alpha, int flags, const int* __restrict__ dflag)
{
  const int isbf = *dflag;
  const int bz = blockIdx.z;
  A  += (long)bz * strideA;
  const long bB = offB + (long)bz * strideB;
  const long cBase = (long)bz * strideC;
  const long bBias = offBias + (long)bz * strideBias;
  __shared__ float sA[16][68];
  __shared__ float sB[16][64];
  const int tid = threadIdx.x;
  const int tx = tid & 15, ty = tid >> 4;
  const int m0 = blockIdx.y * 64, n0 = blockIdx.x * 64;
  float acc[4][4];
#pragma unroll
  for (int i=0;i<4;i++)
#pragma unroll
    for (int j=0;j<4;j++) acc[i][j]=0.f;

  for (int k0 = 0; k0 < K; k0 += 16) {
#pragma unroll
    for (int r = 0; r < 4; r++) {
      int lin = tid + r*256;
      int kk = lin & 15, m = lin >> 4;
      int gm = m0 + m, gk = k0 + kk;
      sA[kk][m] = (gm < M && gk < K) ? A[(long)gm*lda + gk] : 0.f;
    }
#pragma unroll
    for (int r = 0; r < 4; r++) {
      int lin = tid + r*256;
      int nn = lin & 63, kk = lin >> 6;
      int gn = n0 + nn, gk = k0 + kk;
      sB[kk][nn] = (gn < N && gk < K) ? ldin(Bw, bB + (long)gk*ldb + gn, isbf) : 0.f;
    }
    __syncthreads();
#pragma unroll
    for (int kk = 0; kk < 16; kk++) {
      const float4 a4 = *(const float4*)(&sA[kk][ty*4]);
      const float4 b4 = *(const float4*)(&sB[kk][tx*4]);
      float av[4] = {a4.x, a4.y, a4.z, a4.w};
      float bv[4] = {b4.x, b4.y, b4.z, b4.w};
#pragma unroll
      for (int i=0;i<4;i++)
#pragma unroll
        for (int j=0;j<4;j++) acc[i][j] += av[i]*bv[j];
    }
    __syncthreads();
  }
#pragma unroll
  for (int i=0;i<4;i++) {
    const int gm = m0 + ty*4 + i;
    if (gm >= M) continue;
#pragma unroll
    for (int j=0;j<4;j++) {
      const int gn = n0 + tx*4 + j;
      if (gn >= N) continue;
      float vv = acc[i][j]*alpha;
      if (flags & 1) vv += ldin(bias, bBias + gn, isbf);
      if (flags & 4) vv = geluf(vv);
      const long idx = cBase + (long)gm*ldc + gn;
      if (flags & 8) {
        ((unsigned short*)C)[idx] = f2bu(vv);
      } else {
        if (flags & 2) vv += C[idx];
        C[idx] = vv;
      }
    }
  }
}

// ---------------- gate16: g16[row][0..15] = xc[row]@w_if + b_if  (N=16 specialized) ----------------
// grid 504 x 256thr; w_if staged in LDS fp32 [1024][17] (stride 17 -> conflict-free)
__global__ __launch_bounds__(256) void gate16(
    const float* __restrict__ xc, const void* __restrict__ wif, long offW,
    const void* __restrict__ bif, long offB, float* __restrict__ g16,
    const int* __restrict__ dflag)
{
  const int isbf = *dflag;
  __shared__ float wl[1024*17];
  const int tid = threadIdx.x;
  for (int i = tid; i < 16384; i += 256){
    const int k = i >> 4, j = i & 15;
    wl[k*17 + j] = ldin(wif, offW + (long)k*16 + j, isbf);
  }
  const int w = tid >> 6, l = tid & 63;
  const float bv = (l < 16) ? ldin(bif, offB + l, isbf) : 0.f;
  __syncthreads();

#pragma unroll
  for (int i = 0; i < 4; i++){
    const int row = blockIdx.x*16 + w*4 + i;
    const float* xr = xc + (long)row*DI_;
    float acc[16];
#pragma unroll
    for (int j=0;j<16;j++) acc[j] = 0.f;
#pragma unroll
    for (int kk = 0; kk < 16; kk++){
      const float xv = xr[kk*64 + l];
      const float* wp = &wl[(kk*64 + l)*17];
#pragma unroll
      for (int j=0;j<16;j++) acc[j] += xv * wp[j];
    }
#pragma unroll
    for (int j=0;j<16;j++){
      acc[j] += __shfl_xor(acc[j], 32);
      acc[j] += __shfl_xor(acc[j], 16);
      acc[j] += __shfl_xor(acc[j], 8);
      acc[j] += __shfl_xor(acc[j], 4);
      acc[j] += __shfl_xor(acc[j], 2);
      acc[j] += __shfl_xor(acc[j], 1);
    }
    if (l < 16){
      float out = acc[0];
#pragma unroll
      for (int j=1;j<16;j++) if (l == j) out = acc[j];
      g16[(long)row*16 + l] = out + bv;
    }
  }
}

// ---------------- sLSTM scan v4: 512 threads, 2 threads per (gate,e), 32 wts/thread ----------------
__global__ __launch_bounds__(512, 1) void slstm_scan4(
    const float* __restrict__ g4, const float* __restrict__ wR,
    float* __restrict__ hs)
{
  const int blk = blockIdx.x;
  const int b = blk >> 3, hd = blk & 7;
  const int tid = threadIdx.x;
  const int g = tid >> 7;
  const int e = (tid >> 1) & 63;
  const int half = tid & 1;

  float4 w[8];
  {
    const float* p = wR + (((long)g*8 + hd)*64 + e)*64 + half*32;
#pragma unroll
    for (int d4 = 0; d4 < 8; d4++) w[d4] = *(const float4*)(p + d4*4);
  }

  __shared__ float hlds[64];
  __shared__ float rec[4][64];
  if (tid < 64) hlds[tid] = 0.f;
  float c = 0.f, n = 0.f, m = 0.f;
  __syncthreads();

  const long gbase = (long)g*BT_*D_ + (long)(b*T_)*D_ + hd*64 + e;
  float gnext = (half == 0) ? g4[gbase] : 0.f;

  for (int t = 0; t < T_; t++) {
    const float gc = gnext;
    if (half == 0 && t+1 < T_) gnext = g4[gbase + (long)(t+1)*D_];
    float r = 0.f;
    const float* hb = &hlds[half*32];
#pragma unroll
    for (int d4 = 0; d4 < 8; d4++) {
      const float4 hv = *(const float4*)(hb + d4*4);
      r += w[d4].x*hv.x + w[d4].y*hv.y + w[d4].z*hv.z + w[d4].w*hv.w;
    }
    r += __shfl_xor(r, 1);
    if (half == 0) {
      r += gc;
      if (g == 2) r = tanhf(r);
      else if (g == 3) r = 1.f/(1.f+expf(-r));
      rec[g][e] = r;
    }
    __syncthreads();
    if (tid < 64) {
      const int es = tid;
      const float it = rec[0][es], ft = rec[1][es];
      const float zt = rec[2][es];
      const float ot = rec[3][es];
      const float mn = fmaxf(ft + m, it);
      const float ig = expf(it - mn);
      const float fg = expf(ft + m - mn);
      c = fg*c + ig*zt;
      n = fg*n + ig;
      m = mn;
      const float hn = ot*c/fmaxf(n, 1e-6f);
      hlds[es] = hn;
      hs[(long)(b*T_+t)*D_ + hd*64 + es] = hn;
    }
    __syncthreads();
  }
}

// ---------------- sLSTM scan (fallback, reads raw Rg) ----------------
__global__ __launch_bounds__(256) void slstm_scan(
    const float* __restrict__ g4, const void* __restrict__ Rg, long offR,
    float* __restrict__ hs, const int* __restrict__ dflag)
{
  const int isbf = *dflag;
  const int blk = blockIdx.x;
  const int b = blk >> 3, hd = blk & 7;
  const int tid = threadIdx.x;
  const int g = tid >> 6, e = tid & 63;
  float w[64];
  {
    const long wp = offR + ((long)(g*NH_ + hd)*64)*64 + e;
#pragma unroll
    for (int d = 0; d < 64; d++) w[d] = ldin(Rg, wp + d*64, isbf);
  }
  __shared__ float hlds[64];
  __shared__ float rec[4][64];
  if (tid < 64) hlds[tid] = 0.f;
  float c = 0.f, n = 0.f, m = 0.f;
  __syncthreads();
  const long gate_base = (long)(b*T_)*D_ + hd*64 + e;
  for (int t = 0; t < T_; t++) {
    float r = 0.f;
#pragma unroll
    for (int d4 = 0; d4 < 16; d4++) {
      const float4 hv = *(const float4*)(&hlds[d4*4]);
      r += w[4*d4]*hv.x + w[4*d4+1]*hv.y + w[4*d4+2]*hv.z + w[4*d4+3]*hv.w;
    }
    r += g4[(long)g*BT_*D_ + gate_base + (long)t*D_];
    rec[g][e] = r;
    __syncthreads();
    if (tid < 64) {
      const float it = rec[0][e], ft = rec[1][e];
      const float zt = tanhf(rec[2][e]);
      const float ot = 1.f/(1.f+expf(-rec[3][e]));
      const float mn = fmaxf(ft + m, it);
      const float ig = expf(it - mn);
      const float fg = expf(ft + m - mn);
      c = fg*c + ig*zt;
      n = fg*n + ig;
      m = mn;
      const float hn = ot*c/fmaxf(n, 1e-6f);
      hlds[e] = hn;
      hs[(long)(b*T_+t)*D_ + hd*64 + e] = hn;
    }
    __syncthreads();
  }
}

// ---------------- head_norm(dh=64) * gn, accumulated into h ----------------
__global__ __launch_bounds__(64) void hn_add(
    const float* __restrict__ hs, const void* __restrict__ gn, long offG,
    float* __restrict__ h, const int* __restrict__ dflag)
{
  const int isbf = *dflag;
  const int blk = blockIdx.x;
  const int bt = blk >> 3, hd = blk & 7;
  const int e = threadIdx.x;
  const long idx = (long)bt*D_ + hd*64 + e;
  const float x = hs[idx];
  float s1 = x, s2 = x*x;
#pragma unroll
  for (int o = 32; o > 0; o >>= 1) { s1 += __shfl_xor(s1, o); s2 += __shfl_xor(s2, o); }
  const float mu = s1*(1.f/64.f);
  const float var = s2*(1.f/64.f) - mu*mu;
  const float y = (x-mu)*rsqrtf(var+EPS_)*ldin(gn, offG + hd*64+e, isbf);
  h[idx] += y;
}

// ---------------- FF gating: gelu(g)*up, written with 704 stride (zero pad) ----------------
__global__ void ffgate(const float* __restrict__ u, float* __restrict__ out)
{
  const long total = (long)BT_*FFP_;
  for (long idx = (long)blockIdx.x*256 + threadIdx.x; idx < total;
       idx += (long)gridDim.x*256) {
    const long m = idx / FFP_;
    const int j = (int)(idx % FFP_);
    float r = 0.f;
    if (j < FF_) {
      const float g = u[m*FF2_ + j];
      r = geluf(g) * u[m*FF2_ + FF_ + j];
    }
    out[idx] = r;
  }
}

// ---------------- mLSTM gate cumsum: one block per (b, head) ----------------
__global__ __launch_bounds__(256) void mlstm_cf(
    const float* __restrict__ g16, float* __restrict__ cf, float* __restrict__ logi)
{
  const int bh = blockIdx.x;
  const int b = bh >> 3, hd = bh & 7;
  const int tid = threadIdx.x;
  __shared__ float slf[T_];
  if (tid < T_) {
    const float gf = g16[(long)(b*T_+tid)*16 + 8 + hd];
    const float ls = (gf >= 0.f) ? -log1pf(expf(-gf)) : (gf - log1pf(expf(gf)));
    slf[tid] = ls;
    logi[(long)bh*T_ + tid] = g16[(long)(b*T_+tid)*16 + hd];
  }
  __syncthreads();
  if (tid == 0) {
    float a = 0.f;
    for (int t = 0; t < T_; t++) { a += slf[t]; slf[t] = a; }
  }
  __syncthreads();
  if (tid < T_) cf[(long)bh*T_ + tid] = slf[tid];
}

// ---------------- MFMA flash attention ----------------
#define QPD 136
#define VPD 72
__global__ __launch_bounds__(256) void attn_mfma(
    const float* __restrict__ q, const unsigned short* __restrict__ k,
    const unsigned short* __restrict__ v, const float* __restrict__ cf,
    const float* __restrict__ li, float* __restrict__ hatt)
{
  const int tt = blockIdx.x, bh = blockIdx.y;
  const int b = bh >> 3, hd = bh & 7;
  const int t0 = tt*64;
  const int tid = threadIdx.x;
  const int w = tid >> 6, lane = tid & 63;
  const int lr = lane & 15, lq = lane >> 4;

  __shared__ unsigned short sQ[64*QPD];
  __shared__ unsigned short sK[64*QPD];
  __shared__ unsigned short sVt[128*VPD];
  __shared__ unsigned short sS[64*VPD];
  __shared__ float scft[64], scfs[64], slis[64];

  for (int idx = tid; idx < 64*64; idx += 256){
    int r = idx >> 6, dp = idx & 63;
    int t = t0 + r;
    unsigned pk = 0;
    if (t < T_){
      const float* qp = q + ((long)(b*T_+t))*DI_ + hd*DHI_ + dp*2;
      pk = packbf(qp[0], qp[1]);
    }
    *(unsigned*)&sQ[r*QPD + dp*2] = pk;
  }
  if (tid < 64) scft[tid] = (t0+tid < T_) ? cf[(long)bh*T_ + t0+tid] : 0.f;

  float m_st[4], s_st[4], alpha_[4];
#pragma unroll
  for (int rr=0;rr<4;rr++){ m_st[rr] = -INFINITY; s_st[rr] = 0.f; }
  floatx4 accO[8];
#pragma unroll
  for (int nd=0;nd<8;nd++)
#pragma unroll
    for (int rr=0;rr<4;rr++) accO[nd][rr] = 0.f;

  for (int st = 0; st <= tt; st++){
    const int s0 = st*64;
    for (int idx = tid; idx < 64*64; idx += 256){
      int r = idx >> 6, dp = idx & 63;
      int s = s0 + r;
      unsigned pkk = 0, pkv = 0;
      if (s < T_){
        const long base = ((long)(b*T_+s))*DI_ + hd*DHI_ + dp*2;
        pkk = *(const unsigned*)&k[base];
        pkv = *(const unsigned*)&v[base];
      }
      *(unsigned*)&sK[r*QPD + dp*2] = pkk;
      sVt[(dp*2)*VPD + r]   = (unsigned short)(pkv & 0xFFFFu);
      sVt[(dp*2+1)*VPD + r] = (unsigned short)(pkv >> 16);
    }
    if (tid < 64){
      int s = s0 + tid;
      scfs[tid] = (s < T_) ? cf[(long)bh*T_ + s] : 0.f;
      slis[tid] = (s < T_) ? li[(long)bh*T_ + s] : 0.f;
    }
    __syncthreads();

    floatx4 accS[4];
#pragma unroll
    for (int ni=0;ni<4;ni++)
#pragma unroll
      for (int rr=0;rr<4;rr++) accS[ni][rr] = 0.f;
    const int qrow = w*16 + lr;
#pragma unroll
    for (int k0=0;k0<4;k0++){
      short8 a = *(const short8*)&sQ[qrow*QPD + k0*32 + lq*8];
#pragma unroll
      for (int ni=0;ni<4;ni++){
        short8 bb = *(const short8*)&sK[(ni*16+lr)*QPD + k0*32 + lq*8];
        accS[ni] = __builtin_amdgcn_mfma_f32_16x16x32_bf16(a, bb, accS[ni], 0,0,0);
      }
    }

#pragma unroll
    for (int rr=0;rr<4;rr++){
      const int tg = t0 + w*16 + lq*4 + rr;
      const float cftr = scft[w*16 + lq*4 + rr];
      float dmv[4];
      float mx = -INFINITY;
#pragma unroll
      for (int ni=0;ni<4;ni++){
        const int sg = s0 + ni*16 + lr;
        const bool valid = (tg < T_) && (sg <= tg);
        dmv[ni] = valid ? (cftr - scfs[ni*16+lr] + slis[ni*16+lr]) : -INFINITY;
        mx = fmaxf(mx, dmv[ni]);
      }
      mx = fmaxf(mx, __shfl_xor(mx, 1));
      mx = fmaxf(mx, __shfl_xor(mx, 2));
      mx = fmaxf(mx, __shfl_xor(mx, 4));
      mx = fmaxf(mx, __shfl_xor(mx, 8));
      const float mnew = fmaxf(m_st[rr], mx);
      const float al = (mnew == -INFINITY) ? 0.f : expf(m_st[rr] - mnew);
      float rs = 0.f;
#pragma unroll
      for (int ni=0;ni<4;ni++){
        const float wexp = (dmv[ni] == -INFINITY) ? 0.f : expf(dmv[ni] - mnew);
        const float pv = accS[ni][rr]*wexp;
        rs += pv;
        sS[(w*16 + lq*4 + rr)*VPD + ni*16 + lr] = f2bu(pv);
      }
      rs += __shfl_xor(rs, 1);
      rs += __shfl_xor(rs, 2);
      rs += __shfl_xor(rs, 4);
      rs += __shfl_xor(rs, 8);
      s_st[rr] = s_st[rr]*al + rs;
      m_st[rr] = mnew;
      alpha_[rr] = al;
    }

#pragma unroll
    for (int nd=0;nd<8;nd++)
#pragma unroll
      for (int rr=0;rr<4;rr++) accO[nd][rr] *= alpha_[rr];

#pragma unroll
    for (int ks=0;ks<2;ks++){
      short8 aP = *(const short8*)&sS[(w*16 + lr)*VPD + ks*32 + lq*8];
#pragma unroll
      for (int nd=0;nd<8;nd++){
        short8 bV = *(const short8*)&sVt[(nd*16+lr)*VPD + ks*32 + lq*8];
        accO[nd] = __builtin_amdgcn_mfma_f32_16x16x32_bf16(aP, bV, accO[nd], 0,0,0);
      }
    }
    __syncthreads();
  }

#pragma unroll
  for (int rr=0;rr<4;rr++){
    const int tg = t0 + w*16 + lq*4 + rr;
    if (tg >= T_) continue;
    const float inv = 1.f / fmaxf(fabsf(s_st[rr]), expf(-m_st[rr]));
    float* op = hatt + ((long)(b*T_+tg))*DI_ + hd*DHI_;
#pragma unroll
    for (int nd=0;nd<8;nd++)
      op[nd*16 + lr] = accO[nd][rr]*inv;
  }
}

// ---------------- head_norm(dh=128)*gn + skip*xc, then *silu(z) ----------------
__global__ __launch_bounds__(128) void hn_mlstm(
    const float* __restrict__ hatt, const void* __restrict__ gn, long offG,
    const void* __restrict__ skip, long offSk, const float* __restrict__ xc,
    const float* __restrict__ u, float* __restrict__ gin,
    const int* __restrict__ dflag)
{
  const int isbf = *dflag;
  const int blk = blockIdx.x;
  const int bt = blk >> 3, hd = blk & 7;
  const int e = threadIdx.x;
  const int j = hd*DHI_ + e;
  const long idx = (long)bt*DI_ + j;
  const float x = hatt[idx];
  __shared__ float r1[128], r2[128];
  r1[e]=x; r2[e]=x*x; __syncthreads();
  for (int o=64;o>0;o>>=1){ if(e<o){r1[e]+=r1[e+o]; r2[e]+=r2[e+o];} __syncthreads(); }
  const float mu = r1[0]*(1.f/128.f);
  const float var = r2[0]*(1.f/128.f)-mu*mu;
  const float y = (x-mu)*rsqrtf(var+EPS_)*ldin(gn, offG+j, isbf) + ldin(skip, offSk+j, isbf)*xc[idx];
  const float z = u[(long)bt*2048 + DI_ + j];
  gin[idx] = y * siluf(z);
}

// ---------------- final transpose to output ----------------
__global__ void out_transpose(const float* __restrict__ hp, void* __restrict__ out,
                              const int* __restrict__ dflag)
{
  const int isbf = *dflag;
  const int tid = threadIdx.x;
  if (tid < B_*6) {
    const int b = tid / 6, hd = tid % 6;
    const float v = hp[hd*B_ + b];
    if (isbf) ((bf16*)out)[tid] = __float2bfloat16(v);
    else      ((float*)out)[tid] = v;
  }
}

extern "C" void kernel_launch(void* const* d_in, const int* in_sizes, int n_in,
                              void* d_out, int out_size, void* d_ws, size_t ws_size,
                              hipStream_t stream)
{
  (void)in_sizes; (void)n_in; (void)out_size;
  const void* x        = d_in[0];
  const void* w_in     = d_in[1];
  const void* b_in     = d_in[2];
  const void* ln_in_s  = d_in[3];
  const void* ln_in_b  = d_in[4];
  const void* s_ln_s   = d_in[5];
  const void* s_ln_b   = d_in[6];
  const void* s_conv_w = d_in[7];
  const void* s_conv_b = d_in[8];
  const void* s_wg     = d_in[9];
  const void* s_rg     = d_in[10];
  const void* s_bg     = d_in[11];
  const void* s_gn     = d_in[12];
  const void* s_ffln_s = d_in[13];
  const void* s_ffln_b = d_in[14];
  const void* s_ff_w1  = d_in[15];
  const void* s_ff_w2  = d_in[16];
  const void* m_ln_s   = d_in[17];
  const void* m_ln_b   = d_in[18];
  const void* m_w_up   = d_in[19];
  const void* m_conv_w = d_in[20];
  const void* m_conv_b = d_in[21];
  const void* m_wq     = d_in[22];
  const void* m_wk     = d_in[23];
  const void* m_wv     = d_in[24];
  const void* m_w_if   = d_in[25];
  const void* m_b_if   = d_in[26];
  const void* m_skip   = d_in[27];
  const void* m_gn     = d_in[28];
  const void* m_w_down = d_in[29];
  const void* post_ln_s= d_in[30];
  const void* post_ln_b= d_in[31];
  const void* hw1      = d_in[32];
  const void* hb1      = d_in[33];
  const void* hw2      = d_in[34];
  const void* hb2      = d_in[35];
  const void* hw3      = d_in[36];
  const void* hb3      = d_in[37];

  float* W   = (float*)d_ws;
  float* h   = W;                           // BT*D
  float* xn  = W + 4128768L;                // BT*D
  float* xc  = W + 8257536L;                // BT*DI
  float* u   = W + 16515072L;               // 4*BT*D
  float* q   = W + 33030144L;               // BT*DI fp32 (hs / ffg(704) / hatt / gin)
  unsigned short* kk_ = (unsigned short*)(W + 41287680L); // BT*DI bf16
  unsigned short* vv_ = (unsigned short*)(W + 45416448L); // BT*DI bf16
  float* g16 = W + 49545216L;               // BT*16
  float* cfb = W + 49674240L;               // B*NH*T
  float* lib = W + 49738752L;               // B*NH*T
  float* last= W + 49803264L;               // 32*512
  float* ha1 = W + 49819648L;               // 6*32*256
  float* ha2 = W + 49868800L;               // 6*32*128
  float* hp  = W + 49893376L;               // 6*32 (pad)
  int*   dfl = (int*)(W + 49893568L);
  float* wsRg = W + 49893632L;              // 4 layers x 4x8x64x64 fp32 = 524288 floats

  // bf16 weight planes (hi, lo), each PLANE ushorts, k-contiguous [N][K]
  const long PLANE = 14327808L;
  unsigned short* wtHi = (unsigned short*)(W + 50417920L);
  unsigned short* wtLo = wtHi + PLANE;
  const long oWg=0, oF1=4194304L, oF2=6987776L, oUp=8429568L;
  const long oQ=11575296L, oK=11968512L, oV=12361728L, oDn=12754944L;

  const size_t needFull = (size_t)(50417920L + PLANE)*4;            // ~259.0 MB
  const size_t needMid  = (size_t)(50417920L + PLANE/2)*4 + PLANE;  // tier1: hi plane only
  const int tier = (ws_size >= needFull) ? 2 : ((ws_size >= needMid) ? 1 : 0);
  const int spB = (tier == 2) ? 1 : 0;
  unsigned short* loArg = (tier == 2) ? wtLo : nullptr;

  const float kscale = 0.08838834764831845f; // 1/sqrt(128)

  detect_dtype<<<1, 64, 0, stream>>>((const unsigned*)ln_in_s, dfl);

  if (tier >= 1) {
    rg_prep<<<128, 256, 0, stream>>>(s_rg, wsRg, dfl);
    wt_transpose2<<<dim3(16,16,16),256,0,stream>>>(s_wg, 0, 262144L, 512, 512, 512,
        wtHi+oWg, loArg?loArg+oWg:nullptr, 262144L, dfl);
    wt_transpose2<<<dim3(43,16,4),256,0,stream>>>(s_ff_w1, 0, 698368L, 512, 1364, 512,
        wtHi+oF1, loArg?loArg+oF1:nullptr, 698368L, dfl);
    wt_transpose2<<<dim3(16,22,4),256,0,stream>>>(s_ff_w2, 0, 349184L, 682, 512, 704,
        wtHi+oF2, loArg?loArg+oF2:nullptr, 360448L, dfl);
    wt_transpose2<<<dim3(64,16,3),256,0,stream>>>(m_w_up, 0, 1048576L, 512, 2048, 512,
        wtHi+oUp, loArg?loArg+oUp:nullptr, 1048576L, dfl);
    wt_transpose2<<<dim3(4,4,24),256,0,stream>>>(m_wq, 0, 16384L, 128, 128, 128,
        wtHi+oQ, loArg?loArg+oQ:nullptr, 16384L, dfl);
    wt_transpose2<<<dim3(4,4,24),256,0,stream>>>(m_wk, 0, 16384L, 128, 128, 128,
        wtHi+oK, loArg?loArg+oK:nullptr, 16384L, dfl);
    wt_transpose2<<<dim3(4,4,24),256,0,stream>>>(m_wv, 0, 16384L, 128, 128, 128,
        wtHi+oV, loArg?loArg+oV:nullptr, 16384L, dfl);
    wt_transpose2<<<dim3(16,32,3),256,0,stream>>>(m_w_down, 0, 524288L, 1024, 512, 1024,
        wtHi+oDn, loArg?loArg+oDn:nullptr, 524288L, dfl);
  }

  ln_proj<<<BT_, 256, 0, stream>>>(x, w_in, b_in, ln_in_s, ln_in_b, h, dfl);

  int si = 0, mi = 0;
  for (int blk = 0; blk < 7; blk++) {
    if ((blk & 1) == 0) {
      // ---- sLSTM block ----
      ln_rows<<<BT_,256,0,stream>>>(h, 512L, s_ln_s, (long)si*512, s_ln_b, (long)si*512, xn, dfl);
      {
        long tot = (long)BT_*512; int g = (int)((tot+255)/256);
        conv_silu<<<g,256,0,stream>>>(xn, 512, s_conv_w, (long)si*4*512, s_conv_b, (long)si*512, xc, 512, dfl);
      }
      if (tier >= 1) {
        gemm_split<<<dim3(8,126,4),256,0,stream>>>(xc, xn, 2, 0L,
            wtHi+oWg+(long)si*4*262144L, wtLo+oWg+(long)si*4*262144L,
            s_bg, (long)si*4*512, u,
            512, 512, 512, 512, 262144L, (long)BT_*512, 512L, 1.f, 1, spB, dfl);
      } else {
        for (int g = 0; g < 4; g++) {
          const float* Ain = (g < 2) ? xc : xn;
          gemm_f32b<<<dim3(8,126,1),256,0,stream>>>(Ain, s_wg, ((long)(si*4+g))*512*512,
              s_bg, (long)(si*4+g)*512, u + (long)g*BT_*512,
              BT_, 512, 512, 512, 512, 512, 0,0,0,0, 1.f, 1, dfl);
        }
      }
      if (tier >= 1)
        slstm_scan4<<<256,512,0,stream>>>(u, wsRg + (long)si*131072L, q /*hs*/);
      else
        slstm_scan<<<256,256,0,stream>>>(u, s_rg, (long)si*4*8*64*64, q /*hs*/, dfl);
      hn_add<<<BT_*8,64,0,stream>>>(q, s_gn, (long)si*512, h, dfl);
      // ---- FF block ----
      ln_rows<<<BT_,256,0,stream>>>(h, 512L, s_ffln_s, (long)si*512, s_ffln_b, (long)si*512, xn, dfl);
      if (tier >= 1)
        gemm_split<<<dim3(22,126,1),256,0,stream>>>(xn, xn, 9, 0L,
            wtHi+oF1+(long)si*698368L, wtLo+oF1+(long)si*698368L, nullptr, 0,
            u, 1364, 512, 512, 1364, 0,0,0, 1.f, 0, spB, dfl);
      else
        gemm_f32b<<<dim3(22,126,1),256,0,stream>>>(xn, s_ff_w1, (long)si*512*1364, nullptr, 0,
            u, BT_, 1364, 512, 512, 1364, 1364, 0,0,0,0, 1.f, 0, dfl);
      {
        long tot = (long)BT_*FFP_; int g = (int)((tot+255)/256);
        ffgate<<<g,256,0,stream>>>(u, q /*ffg, stride 704*/);
      }
      if (tier >= 1)
        gemm_split<<<dim3(8,126,1),256,0,stream>>>(q, q, 9, 0L,
            wtHi+oF2+(long)si*360448L, wtLo+oF2+(long)si*360448L, nullptr, 0,
            h, 512, 704, 704, 512, 0,0,0, 1.f, 2, spB, dfl);
      else
        gemm_f32b<<<dim3(8,126,1),256,0,stream>>>(q, s_ff_w2, (long)si*682*512, nullptr, 0,
            h, BT_, 512, 682, 704, 512, 512, 0,0,0,0, 1.f, 2, dfl);
      si++;
    } else {
      // ---- mLSTM block ----
      ln_rows<<<BT_,256,0,stream>>>(h, 512L, m_ln_s, (long)mi*512, m_ln_b, (long)mi*512, xn, dfl);
      if (tier >= 1)
        gemm_split<<<dim3(32,126,1),256,0,stream>>>(xn, xn, 9, 0L,
            wtHi+oUp+(long)mi*1048576L, wtLo+oUp+(long)mi*1048576L, nullptr, 0,
            u, 2048, 512, 512, 2048, 0,0,0, 1.f, 0, spB, dfl);
      else
        gemm_f32b<<<dim3(32,126,1),256,0,stream>>>(xn, m_w_up, (long)mi*512*2048, nullptr, 0,
            u, BT_, 2048, 512, 512, 2048, 2048, 0,0,0,0, 1.f, 0, dfl);
      {
        long tot = (long)BT_*1024; int g = (int)((tot+255)/256);
        conv_silu<<<g,256,0,stream>>>(u, 2048, m_conv_w, (long)mi*4*1024, m_conv_b, (long)mi*1024, xc, 1024, dfl);
      }
      if (tier >= 1) {
        gemm_split<<<dim3(2,126,8),256,0,stream>>>(xc, xc, 9, 128L,
            wtHi+oQ+(long)mi*131072L, wtLo+oQ+(long)mi*131072L, nullptr, 0,
            q, 128, 128, 1024, 1024, 16384L, 128L, 0, 1.f, 0, spB, dfl);
        gemm_split<<<dim3(2,126,8),256,0,stream>>>(xc, xc, 9, 128L,
            wtHi+oK+(long)mi*131072L, wtLo+oK+(long)mi*131072L, nullptr, 0,
            (float*)kk_, 128, 128, 1024, 1024, 16384L, 128L, 0, kscale, 8, spB, dfl);
        gemm_split<<<dim3(2,126,8),256,0,stream>>>(u, u, 9, 128L,
            wtHi+oV+(long)mi*131072L, wtLo+oV+(long)mi*131072L, nullptr, 0,
            (float*)vv_, 128, 128, 2048, 1024, 16384L, 128L, 0, 1.f, 8, spB, dfl);
      } else {
        gemm_f32b<<<dim3(2,126,8),256,0,stream>>>(xc, m_wq, (long)mi*8*128*128, nullptr, 0,
            q, BT_, 128, 128, 1024, 128, 1024, 128, 16384, 128, 0, 1.f, 0, dfl);
        gemm_f32b<<<dim3(2,126,8),256,0,stream>>>(xc, m_wk, (long)mi*8*128*128, nullptr, 0,
            (float*)kk_, BT_, 128, 128, 1024, 128, 1024, 128, 16384, 128, 0, kscale, 8, dfl);
        gemm_f32b<<<dim3(2,126,8),256,0,stream>>>(u, m_wv, (long)mi*8*128*128, nullptr, 0,
            (float*)vv_, BT_, 128, 128, 2048, 128, 1024, 128, 16384, 128, 0, 1.f, 8, dfl);
      }
      gate16<<<504,256,0,stream>>>(xc, m_w_if, (long)mi*1024*16, m_b_if, (long)mi*16, g16, dfl);
      mlstm_cf<<<256,256,0,stream>>>(g16, cfb, lib);
      attn_mfma<<<dim3(4,256),256,0,stream>>>(q, kk_, vv_, cfb, lib, q /*hatt in-place*/);
      hn_mlstm<<<BT_*8,128,0,stream>>>(q, m_gn, (long)mi*1024, m_skip, (long)mi*1024, xc, u, q, dfl);
      if (tier >= 1)
        gemm_split<<<dim3(8,126,1),256,0,stream>>>(q, q, 9, 0L,
            wtHi+oDn+(long)mi*524288L, wtLo+oDn+(long)mi*524288L, nullptr, 0,
            h, 512, 1024, 1024, 512, 0,0,0, 1.f, 2, spB, dfl);
      else
        gemm_f32b<<<dim3(8,126,1),256,0,stream>>>(q, m_w_down, (long)mi*1024*512, nullptr, 0,
            h, BT_, 512, 1024, 1024, 512, 512, 0,0,0,0, 1.f, 2, dfl);
      mi++;
    }
  }

  // post-LN on last timestep rows only
  ln_rows<<<B_,256,0,stream>>>(h + (long)(T_-1)*512, (long)T_*512, post_ln_s, 0, post_ln_b, 0, last, dfl);

  // 6 prediction heads, batched over grid.z (tiny; SIMT fp32)
  gemm_f32b<<<dim3(4,1,6),256,0,stream>>>(last, hw1, 0, hb1, 0, ha1, 32, 256, 512, 512, 256, 256,
        0, 512L*256, 32L*256, 256, 1.f, 1|4, dfl);
  gemm_f32b<<<dim3(2,1,6),256,0,stream>>>(ha1, hw2, 0, hb2, 0, ha2, 32, 128, 256, 256, 128, 128,
        32L*256, 256L*128, 32L*128, 128, 1.f, 1|4, dfl);
  gemm_f32b<<<dim3(1,1,6),256,0,stream>>>(ha2, hw3, 0, hb3, 0, hp, 32, 1, 128, 128, 1, 1,
        32L*128, 128L, 32L, 1, 1.f, 1, dfl);
  out_transpose<<<1,256,0,stream>>>(hp, d_out, dfl);
}